// Round 3
// baseline (209.381 us; speedup 1.0000x reference)
//
#include <hip/hip_runtime.h>

#define NPIX 4096   // 64*64
#define CIN  256
#define CR   64
#define COUT 512
#define NB   8

// ---------------------------------------------------------------------------
// K1: feat[b,o,hw] = sum_c w_reduce[o,c] * x[b,c,hw]   (64x256 GEMM per pixel)
//     also cnorm[b,hw] = sqrt(sum_o feat^2)
// block = 256 threads = 4 waves; wave g handles channel group g (64 in-ch);
// LDS reduction combines the 4 partial outputs. grid = 8*64 = 512 blocks.
// ---------------------------------------------------------------------------
__global__ __launch_bounds__(256) void k1_reduce(
    const float* __restrict__ x, const float* __restrict__ wr,
    float* __restrict__ feat, float* __restrict__ cnorm)
{
  const int bh = blockIdx.x;
  const int b = bh >> 6, h = bh & 63;
  const int w = threadIdx.x & 63;
  const int g = __builtin_amdgcn_readfirstlane(threadIdx.x >> 6);
  const int px = h * 64 + w;

  const float* xb = x + ((size_t)b * CIN + g * 64) * NPIX + px;

  float acc[64];
#pragma unroll
  for (int o = 0; o < 64; ++o) acc[o] = 0.f;

  for (int c4 = 0; c4 < 16; ++c4) {
    const float v0 = xb[(c4 * 4 + 0) * NPIX];
    const float v1 = xb[(c4 * 4 + 1) * NPIX];
    const float v2 = xb[(c4 * 4 + 2) * NPIX];
    const float v3 = xb[(c4 * 4 + 3) * NPIX];
    const int cb = g * 64 + c4 * 4;
#pragma unroll
    for (int o = 0; o < 64; ++o) {
      const float4 ww = *(const float4*)(wr + o * CIN + cb);  // uniform -> s_load
      acc[o] = fmaf(ww.x, v0, acc[o]);
      acc[o] = fmaf(ww.y, v1, acc[o]);
      acc[o] = fmaf(ww.z, v2, acc[o]);
      acc[o] = fmaf(ww.w, v3, acc[o]);
    }
  }

  __shared__ float lds[4][64][64];   // [g][o][w], 64 KB
#pragma unroll
  for (int o = 0; o < 64; ++o) lds[g][o][w] = acc[o];
  __syncthreads();

  // thread (g,w) finalizes outputs o in [g*16, g*16+16)
  float cpart = 0.f;
  float* fb = feat + (size_t)b * CR * NPIX + px;
#pragma unroll
  for (int i = 0; i < 16; ++i) {
    const int o = g * 16 + i;
    const float s = (lds[0][o][w] + lds[1][o][w]) + (lds[2][o][w] + lds[3][o][w]);
    fb[o * NPIX] = s;
    cpart = fmaf(s, s, cpart);
  }

  __shared__ float lp[4][64];
  lp[g][w] = cpart;
  __syncthreads();
  if (g == 0)
    cnorm[b * NPIX + px] = sqrtf((lp[0][w] + lp[1][w]) + (lp[2][w] + lp[3][w]));
}

// ---------------------------------------------------------------------------
// K2: per-pixel 49-neighbor cosine-sim softmax attention -> corr[b,c,hw]
// block = 256 threads = 4 waves over one (b, h) row of 64 pixels.
// Phase A: wave g computes dot/sim for k in {g, g+4, ...} (13/12/12/12 split).
// Phase B: every thread does the 49-wide softmax for its pixel (redundant x4).
// Phase C: wave g produces out-channels c in [g*16, g*16+16).
// OOB neighbors: loads fall into a guard zone before feat (or trailing ws
// regions) and are select-masked to 0 before use -> matches zero padding.
// ---------------------------------------------------------------------------
__global__ __launch_bounds__(256) void k2_corr(
    const float* __restrict__ feat, const float* __restrict__ cnorm,
    float* __restrict__ corr)
{
  const int bh = blockIdx.x;
  const int b = bh >> 6, h = bh & 63;
  const int w = threadIdx.x & 63;
  const int g = __builtin_amdgcn_readfirstlane(threadIdx.x >> 6);
  const int px = h * 64 + w;

  const float* fb = feat + (size_t)b * CR * NPIX + px;
  const float* cnb = cnorm + b * NPIX + px;

  __shared__ float sim[49][64];

  float fc[64];
#pragma unroll
  for (int c = 0; c < 64; ++c) fc[c] = fb[c * NPIX];
  const float cnc = cnb[0];

  for (int k = g; k < 49; k += 4) {
    const int dy = k / 7 - 3, dx = k % 7 - 3;
    const int nh = h + dy;
    float s = 0.f;
    if ((unsigned)nh < 64u) {
      const int koff = dy * 64 + dx;
      float d0 = 0.f, d1 = 0.f, d2 = 0.f, d3 = 0.f;
#pragma unroll
      for (int c = 0; c < 64; c += 4) {
        d0 = fmaf(fc[c + 0], fb[(c + 0) * NPIX + koff], d0);
        d1 = fmaf(fc[c + 1], fb[(c + 1) * NPIX + koff], d1);
        d2 = fmaf(fc[c + 2], fb[(c + 2) * NPIX + koff], d2);
        d3 = fmaf(fc[c + 3], fb[(c + 3) * NPIX + koff], d3);
      }
      const float dot = (d0 + d1) + (d2 + d3);
      const float cnk = cnb[koff];                 // garbage if col OOB: masked below
      const float sv = dot / fmaxf(cnc * cnk, 1e-8f);
      s = ((unsigned)(w + dx) < 64u) ? sv : 0.f;   // col mask (NaN-safe)
    }
    sim[k][w] = s;
  }
  __syncthreads();

  float att[49];
  float m = -1e30f;
#pragma unroll
  for (int k = 0; k < 49; ++k) { att[k] = sim[k][w]; m = fmaxf(m, att[k]); }
  float sum = 0.f;
#pragma unroll
  for (int k = 0; k < 49; ++k) { const float e = __expf(att[k] - m); att[k] = e; sum += e; }
  const float inv = 1.f / sum;
#pragma unroll
  for (int k = 0; k < 49; ++k) att[k] *= inv;

  float* cb = corr + (size_t)b * CR * NPIX + px;
  for (int ci = 0; ci < 16; ++ci) {
    const int c = g * 16 + ci;
    const float* fcc = fb + c * NPIX;
    float s0 = 0.f, s1 = 0.f, s2 = 0.f, s3 = 0.f;
#pragma unroll
    for (int k = 0; k < 49; ++k) {
      const int dy = k / 7 - 3, dx = k % 7 - 3;   // compile-time
      const int koff = dy * 64 + dx;
      const bool v = ((unsigned)(h + dy) < 64u) & ((unsigned)(w + dx) < 64u);
      const float t = fcc[koff];
      const float p = v ? t : 0.f;                // mask BEFORE fma (NaN-safe)
      if ((k & 3) == 0)      s0 = fmaf(att[k], p, s0);
      else if ((k & 3) == 1) s1 = fmaf(att[k], p, s1);
      else if ((k & 3) == 2) s2 = fmaf(att[k], p, s2);
      else                   s3 = fmaf(att[k], p, s3);
    }
    cb[c * NPIX] = (s0 + s1) + (s2 + s3);
  }
}

// ---------------------------------------------------------------------------
// K3: out[b,o,hw] = sum_c w_proj[o,c] * corr[b,c,hw]   (512x64 GEMM per pixel)
// block = 256 threads, one pixel each, 64-output chunk; grid = 8*16*8 = 1024.
// ---------------------------------------------------------------------------
__global__ __launch_bounds__(256) void k3_proj(
    const float* __restrict__ corr, const float* __restrict__ wp,
    float* __restrict__ out)
{
  const int blk = blockIdx.x;          // b*128 + tile*8 + oc
  const int oc = blk & 7;
  const int tile = (blk >> 3) & 15;
  const int b = blk >> 7;
  const int px = tile * 256 + threadIdx.x;
  const int obase = oc * 64;

  const float* cbp = corr + (size_t)b * CR * NPIX + px;

  float acc[64];
#pragma unroll
  for (int o = 0; o < 64; ++o) acc[o] = 0.f;

  for (int c4 = 0; c4 < 16; ++c4) {
    const float v0 = cbp[(c4 * 4 + 0) * NPIX];
    const float v1 = cbp[(c4 * 4 + 1) * NPIX];
    const float v2 = cbp[(c4 * 4 + 2) * NPIX];
    const float v3 = cbp[(c4 * 4 + 3) * NPIX];
#pragma unroll
    for (int o = 0; o < 64; ++o) {
      const float4 ww = *(const float4*)(wp + (obase + o) * 64 + c4 * 4); // s_load
      acc[o] = fmaf(ww.x, v0, acc[o]);
      acc[o] = fmaf(ww.y, v1, acc[o]);
      acc[o] = fmaf(ww.z, v2, acc[o]);
      acc[o] = fmaf(ww.w, v3, acc[o]);
    }
  }

  float* ob = out + ((size_t)b * COUT + obase) * NPIX + px;
#pragma unroll
  for (int o = 0; o < 64; ++o) ob[o * NPIX] = acc[o];
}

// ---------------------------------------------------------------------------
extern "C" void kernel_launch(void* const* d_in, const int* in_sizes, int n_in,
                              void* d_out, int out_size, void* d_ws, size_t ws_size,
                              hipStream_t stream)
{
  const float* x  = (const float*)d_in[0];
  const float* wr = (const float*)d_in[1];
  const float* wp = (const float*)d_in[2];
  float* out = (float*)d_out;

  // ws layout (floats): [256 guard][feat 8*64*4096][cnorm 8*4096][corr 8*64*4096]
  // total ~16.1 MiB. Guard absorbs negative-offset OOB neighbor reads (masked).
  float* ws    = (float*)d_ws;
  float* feat  = ws + 256;
  float* cnorm = feat + (size_t)NB * CR * NPIX;
  float* corr  = cnorm + (size_t)NB * NPIX;

  hipLaunchKernelGGL(k1_reduce, dim3(NB * 64), dim3(256), 0, stream, x, wr, feat, cnorm);
  hipLaunchKernelGGL(k2_corr,   dim3(NB * 64), dim3(256), 0, stream, feat, cnorm, corr);
  hipLaunchKernelGGL(k3_proj,   dim3(NB * 16 * 8), dim3(256), 0, stream, corr, wp, out);
}

// Round 5
// 207.562 us; speedup vs baseline: 1.0088x; 1.0088x over previous
//
#include <hip/hip_runtime.h>

#define NPIX 4096
#define CIN  256
#define CR   64
#define COUT 512
#define NB   8
#define FG   12544   // featT guard floats each side (covers +-(3*64+3)*64)
#define CG   256     // cnorm guard floats each side (covers +-195)

__device__ __forceinline__ float4 fma4s(float s, float4 v, float4 a) {
  a.x = fmaf(s, v.x, a.x);
  a.y = fmaf(s, v.y, a.y);
  a.z = fmaf(s, v.z, a.z);
  a.w = fmaf(s, v.w, a.w);
  return a;
}

// ---------------------------------------------------------------------------
// K0: transpose weights into ws (wrT[c][o], wpT[c][o]) + zero guard zones.
// grid = 292 blocks * 256 = 74752 = 16384 + 32768 + 2*CG + 2*FG exactly.
// ---------------------------------------------------------------------------
__global__ __launch_bounds__(256) void k0_prep(
    const float* __restrict__ wr, const float* __restrict__ wp,
    float* __restrict__ wrT, float* __restrict__ wpT,
    float* __restrict__ cnorm, float* __restrict__ featT)
{
  const int tid = blockIdx.x * 256 + threadIdx.x;
  if (tid < CR * CIN) {                       // wr[64][256] -> wrT[256][64]
    const int o = tid >> 8, c = tid & 255;
    wrT[c * CR + o] = wr[tid];
  } else if (tid < CR * CIN + COUT * CR) {    // wp[512][64] -> wpT[64][512]
    const int t = tid - CR * CIN;
    const int o = t >> 6, c = t & 63;
    wpT[c * COUT + o] = wp[t];
  } else {
    const int gi = tid - (CR * CIN + COUT * CR);
    if (gi < CG)                cnorm[-CG + gi] = 0.f;
    else if (gi < 2 * CG)       cnorm[NB * NPIX + (gi - CG)] = 0.f;
    else if (gi < 2 * CG + FG)  featT[-FG + (gi - 2 * CG)] = 0.f;
    else                        featT[(size_t)NB * NPIX * CR + (gi - 2 * CG - FG)] = 0.f;
  }
}

// ---------------------------------------------------------------------------
// K1: featT[b,px,c] = sum_k wrT[k][c] * x[b,k,px]; cnorm = sqrt(sum_c feat^2).
// Thread = 16 outs (wave-group g) x 2 px (float2 loads). Weights: wave-uniform
// 16-contiguous-float loads (s_load). 256 blocks x 4 waves.
// ---------------------------------------------------------------------------
__global__ __launch_bounds__(256) void k1_reduce(
    const float* __restrict__ x, const float* __restrict__ wrT,
    float* __restrict__ featT, float* __restrict__ cnorm)
{
  const int blk = blockIdx.x;             // 256 blocks
  const int b = blk >> 5, nt = blk & 31;
  const int lane = threadIdx.x & 63;
  const int g = __builtin_amdgcn_readfirstlane((int)threadIdx.x >> 6);
  const int px = nt * 128 + lane * 2;

  const float* xp = x + (size_t)b * CIN * NPIX + px;
  const float* wb = wrT + g * 16;

  float a0[16], a1[16];
#pragma unroll
  for (int i = 0; i < 16; ++i) { a0[i] = 0.f; a1[i] = 0.f; }

#pragma unroll 2
  for (int k = 0; k < CIN; ++k) {
    const float2 xv = *(const float2*)(xp + (size_t)k * NPIX);
    const float4* wk = (const float4*)(wb + k * CR);
#pragma unroll
    for (int q = 0; q < 4; ++q) {
      const float4 wq = wk[q];
      a0[q*4+0] = fmaf(wq.x, xv.x, a0[q*4+0]);  a1[q*4+0] = fmaf(wq.x, xv.y, a1[q*4+0]);
      a0[q*4+1] = fmaf(wq.y, xv.x, a0[q*4+1]);  a1[q*4+1] = fmaf(wq.y, xv.y, a1[q*4+1]);
      a0[q*4+2] = fmaf(wq.z, xv.x, a0[q*4+2]);  a1[q*4+2] = fmaf(wq.z, xv.y, a1[q*4+2]);
      a0[q*4+3] = fmaf(wq.w, xv.x, a0[q*4+3]);  a1[q*4+3] = fmaf(wq.w, xv.y, a1[q*4+3]);
    }
  }

  // store px-major featT
  float* f0 = featT + (size_t)(b * NPIX + px) * CR + g * 16;
#pragma unroll
  for (int q = 0; q < 4; ++q) {
    *(float4*)(f0 + q * 4)      = make_float4(a0[q*4], a0[q*4+1], a0[q*4+2], a0[q*4+3]);
    *(float4*)(f0 + CR + q * 4) = make_float4(a1[q*4], a1[q*4+1], a1[q*4+2], a1[q*4+3]);
  }

  float p0 = 0.f, p1 = 0.f;
#pragma unroll
  for (int i = 0; i < 16; ++i) { p0 = fmaf(a0[i], a0[i], p0); p1 = fmaf(a1[i], a1[i], p1); }

  __shared__ float lp[4][128];
  lp[g][lane * 2] = p0; lp[g][lane * 2 + 1] = p1;
  __syncthreads();
  if (threadIdx.x < 128) {
    const int j = threadIdx.x;
    const float s = (lp[0][j] + lp[1][j]) + (lp[2][j] + lp[3][j]);
    cnorm[b * NPIX + nt * 128 + j] = sqrtf(s);
  }
}

// ---------------------------------------------------------------------------
// K2: 49-neighbor cosine-sim softmax attention. Block = (b,h) row of 64 px,
// 4 waves. Phase A: wave g computes sims for contiguous k-range (L1-friendly).
// Phase B: redundant per-thread softmax. Phase C: wave g -> c-chunk g*16.
// OOB: guarded (zeroed) loads + coefficient masking (matches zero padding).
// ---------------------------------------------------------------------------
__global__ __launch_bounds__(256) void k2_corr(
    const float* __restrict__ featT, const float* __restrict__ cnorm,
    float* __restrict__ corr)
{
  const int blk = blockIdx.x;          // 512
  const int b = blk >> 6, h = blk & 63;
  const int w = threadIdx.x & 63;
  const int g = __builtin_amdgcn_readfirstlane((int)threadIdx.x >> 6);
  const int px = h * 64 + w;
  const int gpx = b * NPIX + px;

  const float* fT = featT + (size_t)gpx * CR;

  __shared__ float simS[49][64];

  float4 fc[16];
#pragma unroll
  for (int q = 0; q < 16; ++q) fc[q] = *(const float4*)(fT + q * 4);
  const float cnc = cnorm[gpx];

  const int ks = (g * 49) >> 2, ke = ((g + 1) * 49) >> 2;   // {0-12,12-24,24-36,36-49}
  for (int k = ks; k < ke; ++k) {
    const int dy = k / 7 - 3;
    const int dx = k - (dy + 3) * 7 - 3;
    const float* nf = fT + (dy * 64 + dx) * CR;   // may land in zeroed guard
    float d0 = 0.f, d1 = 0.f, d2 = 0.f, d3 = 0.f;
#pragma unroll
    for (int q = 0; q < 16; ++q) {
      const float4 nv = *(const float4*)(nf + q * 4);
      d0 = fmaf(fc[q].x, nv.x, d0);
      d1 = fmaf(fc[q].y, nv.y, d1);
      d2 = fmaf(fc[q].z, nv.z, d2);
      d3 = fmaf(fc[q].w, nv.w, d3);
    }
    const float dot = (d0 + d1) + (d2 + d3);
    const float cnk = cnorm[gpx + dy * 64 + dx];
    const float sim = dot * __builtin_amdgcn_rcpf(fmaxf(cnc * cnk, 1e-8f));
    const bool valid = ((unsigned)(h + dy) < 64u) & ((unsigned)(w + dx) < 64u);
    simS[k][w] = valid ? sim : 0.f;
  }
  __syncthreads();

  float att[49];
  float m = -1e30f;
#pragma unroll
  for (int k = 0; k < 49; ++k) { att[k] = simS[k][w]; m = fmaxf(m, att[k]); }
  float sum = 0.f;
#pragma unroll
  for (int k = 0; k < 49; ++k) { const float e = __expf(att[k] - m); att[k] = e; sum += e; }
  const float inv = __builtin_amdgcn_rcpf(sum);

  float4 cacc[4] = {{0,0,0,0},{0,0,0,0},{0,0,0,0},{0,0,0,0}};
  const float* fTg = fT + g * 16;
#pragma unroll
  for (int k = 0; k < 49; ++k) {
    const int dy = k / 7 - 3, dx = k % 7 - 3;   // compile-time
    const bool valid = ((unsigned)(h + dy) < 64u) & ((unsigned)(w + dx) < 64u);
    const float a = valid ? att[k] * inv : 0.f;  // guard values are finite (zeroed)
    const float* nf = fTg + (dy * 64 + dx) * CR;
#pragma unroll
    for (int q = 0; q < 4; ++q)
      cacc[q] = fma4s(a, *(const float4*)(nf + q * 4), cacc[q]);
  }

  // corr stored c-major for K3's coalesced pixel-vector loads
  float* cb = corr + ((size_t)b * CR + g * 16) * NPIX + px;
#pragma unroll
  for (int q = 0; q < 4; ++q) {
    cb[(q * 4 + 0) * NPIX] = cacc[q].x;
    cb[(q * 4 + 1) * NPIX] = cacc[q].y;
    cb[(q * 4 + 2) * NPIX] = cacc[q].z;
    cb[(q * 4 + 3) * NPIX] = cacc[q].w;
  }
}

// ---------------------------------------------------------------------------
// K3: out[b,o,px] = sum_k wpT[k][o] * corr[b,k,px].
// Thread = 16 outs x 4 px (float4). 1024 blocks x 4 waves.
// ---------------------------------------------------------------------------
__global__ __launch_bounds__(256) void k3_proj(
    const float* __restrict__ corr, const float* __restrict__ wpT,
    float* __restrict__ out)
{
  const int blk = blockIdx.x;   // 1024: b(3b) | mt(3b) | nt(4b)
  const int b = blk >> 7, mt = (blk >> 4) & 7, nt = blk & 15;
  const int lane = threadIdx.x & 63;
  const int g = __builtin_amdgcn_readfirstlane((int)threadIdx.x >> 6);
  const int px = nt * 256 + lane * 4;
  const int og = mt * 64 + g * 16;

  const float* cp = corr + (size_t)b * CR * NPIX + px;
  const float* wb = wpT + og;

  float4 acc[16];
#pragma unroll
  for (int i = 0; i < 16; ++i) acc[i] = make_float4(0.f, 0.f, 0.f, 0.f);

#pragma unroll 2
  for (int k = 0; k < CR; ++k) {
    const float4 cv = *(const float4*)(cp + (size_t)k * NPIX);
    const float4* wk = (const float4*)(wb + k * COUT);
#pragma unroll
    for (int q = 0; q < 4; ++q) {
      const float4 wq = wk[q];
      acc[q*4+0] = fma4s(wq.x, cv, acc[q*4+0]);
      acc[q*4+1] = fma4s(wq.y, cv, acc[q*4+1]);
      acc[q*4+2] = fma4s(wq.z, cv, acc[q*4+2]);
      acc[q*4+3] = fma4s(wq.w, cv, acc[q*4+3]);
    }
  }

  float* ob = out + ((size_t)b * COUT + og) * NPIX + px;
#pragma unroll
  for (int i = 0; i < 16; ++i) *(float4*)(ob + (size_t)i * NPIX) = acc[i];
}

// ---------------------------------------------------------------------------
extern "C" void kernel_launch(void* const* d_in, const int* in_sizes, int n_in,
                              void* d_out, int out_size, void* d_ws, size_t ws_size,
                              hipStream_t stream)
{
  const float* x  = (const float*)d_in[0];
  const float* wr = (const float*)d_in[1];
  const float* wp = (const float*)d_in[2];
  float* out = (float*)d_out;

  // ws layout (floats):
  //   wrT[256*64] | wpT[64*512] | [CG guard] cnorm[8*4096] [CG guard]
  //   [FG guard] featT[8*4096*64] [FG guard] | corr[8*64*4096]
  // total = 4,301,824 floats ~= 16.4 MiB
  float* ws = (float*)d_ws;
  float* wrT   = ws;
  float* wpT   = wrT + CR * CIN;
  float* cnorm = wpT + COUT * CR + CG;
  float* featT = cnorm + NB * NPIX + CG + FG;
  float* corr  = featT + (size_t)NB * NPIX * CR + FG;

  hipLaunchKernelGGL(k0_prep,   dim3(292),  dim3(256), 0, stream, wr, wp, wrT, wpT, cnorm, featT);
  hipLaunchKernelGGL(k1_reduce, dim3(256),  dim3(256), 0, stream, x, wrT, featT, cnorm);
  hipLaunchKernelGGL(k2_corr,   dim3(512),  dim3(256), 0, stream, featT, cnorm, corr);
  hipLaunchKernelGGL(k3_proj,   dim3(1024), dim3(256), 0, stream, corr, wpT, out);
}

// Round 6
// 187.674 us; speedup vs baseline: 1.1157x; 1.1060x over previous
//
#include <hip/hip_runtime.h>

#define NPIX 4096
#define CIN  256
#define CR   64
#define COUT 512
#define NB   8
#define FG   12544   // featT guard floats each side (covers +-(3*64+3)*64)
#define CG   256     // cnorm guard floats each side (covers +-195)

__device__ __forceinline__ float4 fma4s(float s, float4 v, float4 a) {
  a.x = fmaf(s, v.x, a.x);
  a.y = fmaf(s, v.y, a.y);
  a.z = fmaf(s, v.z, a.z);
  a.w = fmaf(s, v.w, a.w);
  return a;
}

// ---------------------------------------------------------------------------
// K0: transpose weights into ws (wrT[c][o], wpT[c][o]) + zero guard zones.
// grid = 292 blocks * 256 = 74752 = 16384 + 32768 + 2*CG + 2*FG exactly.
// ---------------------------------------------------------------------------
__global__ __launch_bounds__(256) void k0_prep(
    const float* __restrict__ wr, const float* __restrict__ wp,
    float* __restrict__ wrT, float* __restrict__ wpT,
    float* __restrict__ cnorm, float* __restrict__ featT)
{
  const int tid = blockIdx.x * 256 + threadIdx.x;
  if (tid < CR * CIN) {                       // wr[64][256] -> wrT[256][64]
    const int o = tid >> 8, c = tid & 255;
    wrT[c * CR + o] = wr[tid];
  } else if (tid < CR * CIN + COUT * CR) {    // wp[512][64] -> wpT[64][512]
    const int t = tid - CR * CIN;
    const int o = t >> 6, c = t & 63;
    wpT[c * COUT + o] = wp[t];
  } else {
    const int gi = tid - (CR * CIN + COUT * CR);
    if (gi < CG)                cnorm[-CG + gi] = 0.f;
    else if (gi < 2 * CG)       cnorm[NB * NPIX + (gi - CG)] = 0.f;
    else if (gi < 2 * CG + FG)  featT[-FG + (gi - 2 * CG)] = 0.f;
    else                        featT[(size_t)NB * NPIX * CR + (gi - 2 * CG - FG)] = 0.f;
  }
}

// ---------------------------------------------------------------------------
// K1: featT[b,px,c] = sum_k wrT[k][c] * x[b,k,px]; cnorm = sqrt(sum_c feat^2).
// Thread = 16 outs (wave-group g) x 2 px (float2 loads). Weights: wave-uniform
// 16-contiguous-float loads (s_load). 256 blocks x 4 waves.
// ---------------------------------------------------------------------------
__global__ __launch_bounds__(256) void k1_reduce(
    const float* __restrict__ x, const float* __restrict__ wrT,
    float* __restrict__ featT, float* __restrict__ cnorm)
{
  const int blk = blockIdx.x;             // 256 blocks
  const int b = blk >> 5, nt = blk & 31;
  const int lane = threadIdx.x & 63;
  const int g = __builtin_amdgcn_readfirstlane((int)threadIdx.x >> 6);
  const int px = nt * 128 + lane * 2;

  const float* xp = x + (size_t)b * CIN * NPIX + px;
  const float* wb = wrT + g * 16;

  float a0[16], a1[16];
#pragma unroll
  for (int i = 0; i < 16; ++i) { a0[i] = 0.f; a1[i] = 0.f; }

#pragma unroll 2
  for (int k = 0; k < CIN; ++k) {
    const float2 xv = *(const float2*)(xp + (size_t)k * NPIX);
    const float4* wk = (const float4*)(wb + k * CR);
#pragma unroll
    for (int q = 0; q < 4; ++q) {
      const float4 wq = wk[q];
      a0[q*4+0] = fmaf(wq.x, xv.x, a0[q*4+0]);  a1[q*4+0] = fmaf(wq.x, xv.y, a1[q*4+0]);
      a0[q*4+1] = fmaf(wq.y, xv.x, a0[q*4+1]);  a1[q*4+1] = fmaf(wq.y, xv.y, a1[q*4+1]);
      a0[q*4+2] = fmaf(wq.z, xv.x, a0[q*4+2]);  a1[q*4+2] = fmaf(wq.z, xv.y, a1[q*4+2]);
      a0[q*4+3] = fmaf(wq.w, xv.x, a0[q*4+3]);  a1[q*4+3] = fmaf(wq.w, xv.y, a1[q*4+3]);
    }
  }

  // store px-major featT
  float* f0 = featT + (size_t)(b * NPIX + px) * CR + g * 16;
#pragma unroll
  for (int q = 0; q < 4; ++q) {
    *(float4*)(f0 + q * 4)      = make_float4(a0[q*4], a0[q*4+1], a0[q*4+2], a0[q*4+3]);
    *(float4*)(f0 + CR + q * 4) = make_float4(a1[q*4], a1[q*4+1], a1[q*4+2], a1[q*4+3]);
  }

  float p0 = 0.f, p1 = 0.f;
#pragma unroll
  for (int i = 0; i < 16; ++i) { p0 = fmaf(a0[i], a0[i], p0); p1 = fmaf(a1[i], a1[i], p1); }

  __shared__ float lp[4][128];
  lp[g][lane * 2] = p0; lp[g][lane * 2 + 1] = p1;
  __syncthreads();
  if (threadIdx.x < 128) {
    const int j = threadIdx.x;
    const float s = (lp[0][j] + lp[1][j]) + (lp[2][j] + lp[3][j]);
    cnorm[b * NPIX + nt * 128 + j] = sqrtf(s);
  }
}

// ---------------------------------------------------------------------------
// K2: 49-neighbor cosine-sim softmax attention. Block = (b,h) row of 64 px,
// 512 threads = 8 waves. XCD-aware mapping: b = blk&7 -> with round-robin
// dispatch, all 64 rows of batch b land on one XCD; featT per batch (1.05 MB)
// fits its 4 MB L2 -> halo loads become L2 hits.
// Phase A: wave g computes sims for k-range [g*49/8,(g+1)*49/8).
// Phase B: redundant per-thread softmax (cheap, VALU).
// Phase C: wave g produces channels [g*8, g*8+8).
// OOB: reads may land in guard zones / adjacent batch rows (finite garbage);
// coefficient is masked to 0 -> matches reference zero padding.
// ---------------------------------------------------------------------------
__global__ __launch_bounds__(512) void k2_corr(
    const float* __restrict__ featT, const float* __restrict__ cnorm,
    float* __restrict__ corr)
{
  const int blk = blockIdx.x;          // 512
  const int b = blk & 7, h = blk >> 3; // XCD-aware: xcd = blk % 8 = b
  const int w = threadIdx.x & 63;
  const int g = __builtin_amdgcn_readfirstlane((int)threadIdx.x >> 6);  // 0..7
  const int px = h * 64 + w;
  const int gpx = b * NPIX + px;

  const float* fT = featT + (size_t)gpx * CR;

  __shared__ float simS[49][64];

  const float cnc = cnorm[gpx];

  {
    float4 fc[16];
#pragma unroll
    for (int q = 0; q < 16; ++q) fc[q] = *(const float4*)(fT + q * 4);

    const int ks = (g * 49) >> 3, ke = ((g + 1) * 49) >> 3;  // 6..7 each
    for (int k = ks; k < ke; ++k) {
      const int dy = k / 7 - 3;
      const int dx = k - (dy + 3) * 7 - 3;
      const float* nf = fT + (dy * 64 + dx) * CR;   // may land in guard/adjacent
      float d0 = 0.f, d1 = 0.f, d2 = 0.f, d3 = 0.f;
#pragma unroll
      for (int q = 0; q < 16; ++q) {
        const float4 nv = *(const float4*)(nf + q * 4);
        d0 = fmaf(fc[q].x, nv.x, d0);
        d1 = fmaf(fc[q].y, nv.y, d1);
        d2 = fmaf(fc[q].z, nv.z, d2);
        d3 = fmaf(fc[q].w, nv.w, d3);
      }
      const float dot = (d0 + d1) + (d2 + d3);
      const float cnk = cnorm[gpx + dy * 64 + dx];
      const float sim = dot * __builtin_amdgcn_rcpf(fmaxf(cnc * cnk, 1e-8f));
      const bool valid = ((unsigned)(h + dy) < 64u) & ((unsigned)(w + dx) < 64u);
      simS[k][w] = valid ? sim : 0.f;
    }
  }
  __syncthreads();

  float att[49];
  float m = -1e30f;
#pragma unroll
  for (int k = 0; k < 49; ++k) { att[k] = simS[k][w]; m = fmaxf(m, att[k]); }
  float sum = 0.f;
#pragma unroll
  for (int k = 0; k < 49; ++k) { const float e = __expf(att[k] - m); att[k] = e; sum += e; }
  const float inv = __builtin_amdgcn_rcpf(sum);

  float4 c0 = {0,0,0,0}, c1 = {0,0,0,0};
  const float* fTg = fT + g * 8;
#pragma unroll
  for (int k = 0; k < 49; ++k) {
    const int dy = k / 7 - 3, dx = k % 7 - 3;   // compile-time
    const bool valid = ((unsigned)(h + dy) < 64u) & ((unsigned)(w + dx) < 64u);
    const float a = valid ? att[k] * inv : 0.f;  // guard values finite
    const float* nf = fTg + (dy * 64 + dx) * CR;
    c0 = fma4s(a, *(const float4*)(nf), c0);
    c1 = fma4s(a, *(const float4*)(nf + 4), c1);
  }

  // corr stored c-major for K3's coalesced pixel-vector loads
  float* cb = corr + ((size_t)b * CR + g * 8) * NPIX + px;
  cb[0 * NPIX] = c0.x;
  cb[1 * NPIX] = c0.y;
  cb[2 * NPIX] = c0.z;
  cb[3 * NPIX] = c0.w;
  cb[4 * NPIX] = c1.x;
  cb[5 * NPIX] = c1.y;
  cb[6 * NPIX] = c1.z;
  cb[7 * NPIX] = c1.w;
}

// ---------------------------------------------------------------------------
// K3: out[b,o,px] = sum_k wpT[k][o] * corr[b,k,px].
// Thread = 16 outs x 4 px (float4). 1024 blocks x 4 waves.
// ---------------------------------------------------------------------------
__global__ __launch_bounds__(256) void k3_proj(
    const float* __restrict__ corr, const float* __restrict__ wpT,
    float* __restrict__ out)
{
  const int blk = blockIdx.x;   // 1024: b(3b) | mt(3b) | nt(4b)
  const int b = blk >> 7, mt = (blk >> 4) & 7, nt = blk & 15;
  const int lane = threadIdx.x & 63;
  const int g = __builtin_amdgcn_readfirstlane((int)threadIdx.x >> 6);
  const int px = nt * 256 + lane * 4;
  const int og = mt * 64 + g * 16;

  const float* cp = corr + (size_t)b * CR * NPIX + px;
  const float* wb = wpT + og;

  float4 acc[16];
#pragma unroll
  for (int i = 0; i < 16; ++i) acc[i] = make_float4(0.f, 0.f, 0.f, 0.f);

#pragma unroll 2
  for (int k = 0; k < CR; ++k) {
    const float4 cv = *(const float4*)(cp + (size_t)k * NPIX);
    const float4* wk = (const float4*)(wb + k * COUT);
#pragma unroll
    for (int q = 0; q < 4; ++q) {
      const float4 wq = wk[q];
      acc[q*4+0] = fma4s(wq.x, cv, acc[q*4+0]);
      acc[q*4+1] = fma4s(wq.y, cv, acc[q*4+1]);
      acc[q*4+2] = fma4s(wq.z, cv, acc[q*4+2]);
      acc[q*4+3] = fma4s(wq.w, cv, acc[q*4+3]);
    }
  }

  float* ob = out + ((size_t)b * COUT + og) * NPIX + px;
#pragma unroll
  for (int i = 0; i < 16; ++i) *(float4*)(ob + (size_t)i * NPIX) = acc[i];
}

// ---------------------------------------------------------------------------
extern "C" void kernel_launch(void* const* d_in, const int* in_sizes, int n_in,
                              void* d_out, int out_size, void* d_ws, size_t ws_size,
                              hipStream_t stream)
{
  const float* x  = (const float*)d_in[0];
  const float* wr = (const float*)d_in[1];
  const float* wp = (const float*)d_in[2];
  float* out = (float*)d_out;

  // ws layout (floats):
  //   wrT[256*64] | wpT[64*512] | [CG guard] cnorm[8*4096] [CG guard]
  //   [FG guard] featT[8*4096*64] [FG guard] | corr[8*64*4096]
  // total = 4,301,824 floats ~= 16.4 MiB
  float* ws = (float*)d_ws;
  float* wrT   = ws;
  float* wpT   = wrT + CR * CIN;
  float* cnorm = wpT + COUT * CR + CG;
  float* featT = cnorm + NB * NPIX + CG + FG;
  float* corr  = featT + (size_t)NB * NPIX * CR + FG;

  hipLaunchKernelGGL(k0_prep,   dim3(292),  dim3(256), 0, stream, wr, wp, wrT, wpT, cnorm, featT);
  hipLaunchKernelGGL(k1_reduce, dim3(256),  dim3(256), 0, stream, x, wrT, featT, cnorm);
  hipLaunchKernelGGL(k2_corr,   dim3(512),  dim3(512), 0, stream, featT, cnorm, corr);
  hipLaunchKernelGGL(k3_proj,   dim3(1024), dim3(256), 0, stream, corr, wpT, out);
}

// Round 7
// 120.165 us; speedup vs baseline: 1.7425x; 1.5618x over previous
//
#include <hip/hip_runtime.h>

#define NPIX 4096
#define CIN  256
#define CR   64
#define COUT 512
#define NB   8
#define CG   256     // cnorm guard floats each side (covers +-195)

__device__ __forceinline__ float4 fma4s(float s, float4 v, float4 a) {
  a.x = fmaf(s, v.x, a.x);
  a.y = fmaf(s, v.y, a.y);
  a.z = fmaf(s, v.z, a.z);
  a.w = fmaf(s, v.w, a.w);
  return a;
}

// ---------------------------------------------------------------------------
// K0: transpose weights (wrT[c][o], wpT[c][o]) + zero cnorm guard zones.
// grid = 194 blocks * 256 = 49664 = 16384 + 32768 + 2*CG exactly.
// ---------------------------------------------------------------------------
__global__ __launch_bounds__(256) void k0_prep(
    const float* __restrict__ wr, const float* __restrict__ wp,
    float* __restrict__ wrT, float* __restrict__ wpT,
    float* __restrict__ cnormG)
{
  const int tid = blockIdx.x * 256 + threadIdx.x;
  if (tid < CR * CIN) {                       // wr[64][256] -> wrT[256][64]
    const int o = tid >> 8, c = tid & 255;
    wrT[c * CR + o] = wr[tid];
  } else if (tid < CR * CIN + COUT * CR) {    // wp[512][64] -> wpT[64][512]
    const int t = tid - CR * CIN;
    const int o = t >> 6, c = t & 63;
    wpT[c * COUT + o] = wp[t];
  } else {
    const int gi = tid - (CR * CIN + COUT * CR);
    if (gi < CG) cnormG[gi] = 0.f;                              // head guard
    else         cnormG[CG + NB * NPIX + (gi - CG)] = 0.f;      // tail guard
  }
}

// ---------------------------------------------------------------------------
// K1: feat[b,c,px] = sum_k wrT[k][c] * x[b,k,px] (c-major output);
//     cnorm[b,px] = sqrt(sum_c feat^2).
// 256 blocks x 512 thr (8 waves). Wave g owns out-channels [g*8, g*8+8);
// thread = 8 outs x 2 px (float2 x loads, coalesced 512B/wave).
// Weight addresses wave-uniform -> s_load. LDS reduce for cnorm.
// ---------------------------------------------------------------------------
__global__ __launch_bounds__(512) void k1_reduce(
    const float* __restrict__ x, const float* __restrict__ wrT,
    float* __restrict__ feat, float* __restrict__ cnorm)
{
  const int blk = blockIdx.x;             // 256 blocks
  const int b = blk >> 5, nt = blk & 31;
  const int lane = threadIdx.x & 63;
  const int g = __builtin_amdgcn_readfirstlane((int)threadIdx.x >> 6);  // 0..7
  const int px = nt * 128 + lane * 2;

  const float* xp = x + (size_t)b * CIN * NPIX + px;
  const float* wb = wrT + g * 8;

  float a0[8], a1[8];
#pragma unroll
  for (int i = 0; i < 8; ++i) { a0[i] = 0.f; a1[i] = 0.f; }

#pragma unroll 4
  for (int k = 0; k < CIN; ++k) {
    const float2 xv = *(const float2*)(xp + (size_t)k * NPIX);
    const float4 w0 = *(const float4*)(wb + k * CR);      // uniform -> s_load
    const float4 w1 = *(const float4*)(wb + k * CR + 4);
    a0[0] = fmaf(w0.x, xv.x, a0[0]);  a1[0] = fmaf(w0.x, xv.y, a1[0]);
    a0[1] = fmaf(w0.y, xv.x, a0[1]);  a1[1] = fmaf(w0.y, xv.y, a1[1]);
    a0[2] = fmaf(w0.z, xv.x, a0[2]);  a1[2] = fmaf(w0.z, xv.y, a1[2]);
    a0[3] = fmaf(w0.w, xv.x, a0[3]);  a1[3] = fmaf(w0.w, xv.y, a1[3]);
    a0[4] = fmaf(w1.x, xv.x, a0[4]);  a1[4] = fmaf(w1.x, xv.y, a1[4]);
    a0[5] = fmaf(w1.y, xv.x, a0[5]);  a1[5] = fmaf(w1.y, xv.y, a1[5]);
    a0[6] = fmaf(w1.z, xv.x, a0[6]);  a1[6] = fmaf(w1.z, xv.y, a1[6]);
    a0[7] = fmaf(w1.w, xv.x, a0[7]);  a1[7] = fmaf(w1.w, xv.y, a1[7]);
  }

  // c-major store: feat[b][c][px], coalesced float2 per channel
#pragma unroll
  for (int i = 0; i < 8; ++i) {
    float2 v = make_float2(a0[i], a1[i]);
    *(float2*)(feat + ((size_t)b * CR + g * 8 + i) * NPIX + px) = v;
  }

  float p0 = 0.f, p1 = 0.f;
#pragma unroll
  for (int i = 0; i < 8; ++i) { p0 = fmaf(a0[i], a0[i], p0); p1 = fmaf(a1[i], a1[i], p1); }

  __shared__ float lp[8][128];
  lp[g][lane * 2] = p0; lp[g][lane * 2 + 1] = p1;
  __syncthreads();
  if (threadIdx.x < 128) {
    const int j = threadIdx.x;
    float s = 0.f;
#pragma unroll
    for (int gg = 0; gg < 8; ++gg) s += lp[gg][j];
    cnorm[b * NPIX + nt * 128 + j] = sqrtf(s);
  }
}

// ---------------------------------------------------------------------------
// K2: fused one-pass 49-neighbor cosine-sim softmax attention (c-major feat).
// Since cosine sim <= 1, exp(sim) never overflows -> NO max pass, NO rescale,
// NO LDS, NO barriers. Block = (b,h) row of 64 px; 4 lanes per px each owning
// 16 channels; dot combined via shfl_xor(1),shfl_xor(2); nf registers reused
// for the weighted accumulation. XCD mapping b=blk&7 keeps feat[b] (1 MB)
// resident in one XCD's L2. OOB k: sim select-masked to 0 (counts in l with
// p=1, matching reference zero-pad semantics) and value-masked out of acc;
// guard garbage is finite (zeroed cnorm guards; feat tail lands in corr).
// ---------------------------------------------------------------------------
__global__ __launch_bounds__(256) void k2_corr(
    const float* __restrict__ feat, const float* __restrict__ cnorm,
    float* __restrict__ corr)
{
  const int blk = blockIdx.x;          // 512
  const int b = blk & 7, h = blk >> 3; // XCD-aware: xcd = blk % 8 = b
  const int t = threadIdx.x;
  const int w = t >> 2;                // px col 0..63
  const int cb = (t & 3) * 16;         // channel base for this lane
  const int px = h * 64 + w;
  const int gpx = b * NPIX + px;

  const float* fpx = feat + (size_t)b * CR * NPIX + (size_t)cb * NPIX + px;
  const float cnc = cnorm[gpx];

  float fc[16];
#pragma unroll
  for (int i = 0; i < 16; ++i) fc[i] = fpx[i * NPIX];

  float acc[16];
#pragma unroll
  for (int i = 0; i < 16; ++i) acc[i] = 0.f;
  float l = 0.f;

  for (int dy = -3; dy <= 3; ++dy) {
    const bool rowok = (unsigned)(h + dy) < 64u;
#pragma unroll
    for (int dx = -3; dx <= 3; ++dx) {
      const int koff = dy * 64 + dx;
      float nf[16];
#pragma unroll
      for (int i = 0; i < 16; ++i) nf[i] = fpx[i * NPIX + koff];
      float d = 0.f;
#pragma unroll
      for (int i = 0; i < 16; ++i) d = fmaf(fc[i], nf[i], d);
      d += __shfl_xor(d, 1);
      d += __shfl_xor(d, 2);
      const float cnk = cnorm[gpx + koff];
      float sim = d * __builtin_amdgcn_rcpf(fmaxf(cnc * cnk, 1e-8f));
      const bool valid = rowok & ((unsigned)(w + dx) < 64u);
      sim = valid ? sim : 0.f;         // select: NaN/Inf-safe
      const float p = __expf(sim);     // sim <= 1 -> p <= e, no overflow
      l += p;
      const float pv = valid ? p : 0.f;  // zero-pad patches contribute 0
#pragma unroll
      for (int i = 0; i < 16; ++i) acc[i] = fmaf(pv, nf[i], acc[i]);
    }
  }

  const float inv = __builtin_amdgcn_rcpf(l);
  float* cp = corr + (size_t)b * CR * NPIX + (size_t)cb * NPIX + px;
#pragma unroll
  for (int i = 0; i < 16; ++i) cp[i * NPIX] = acc[i] * inv;
}

// ---------------------------------------------------------------------------
// K3: out[b,o,px] = sum_k wpT[k][o] * corr[b,k,px].
// Thread = 16 outs x 4 px (float4). 1024 blocks x 256 thr. Block decode puts
// the 8 mt-blocks sharing a (b,nt) corr tile on one XCD (blk%8 = nt%8).
// ---------------------------------------------------------------------------
__global__ __launch_bounds__(256) void k3_proj(
    const float* __restrict__ corr, const float* __restrict__ wpT,
    float* __restrict__ out)
{
  const int blk = blockIdx.x;   // 1024: mt(3b) | b(3b) | nt(4b)
  const int mt = blk >> 7, b = (blk >> 4) & 7, nt = blk & 15;
  const int lane = threadIdx.x & 63;
  const int g = __builtin_amdgcn_readfirstlane((int)threadIdx.x >> 6);
  const int px = nt * 256 + lane * 4;
  const int og = mt * 64 + g * 16;

  const float* cp = corr + (size_t)b * CR * NPIX + px;
  const float* wb = wpT + og;

  float4 acc[16];
#pragma unroll
  for (int i = 0; i < 16; ++i) acc[i] = make_float4(0.f, 0.f, 0.f, 0.f);

#pragma unroll 2
  for (int k = 0; k < CR; ++k) {
    const float4 cv = *(const float4*)(cp + (size_t)k * NPIX);
    const float4* wk = (const float4*)(wb + k * COUT);
#pragma unroll
    for (int q = 0; q < 4; ++q) {
      const float4 wq = wk[q];
      acc[q*4+0] = fma4s(wq.x, cv, acc[q*4+0]);
      acc[q*4+1] = fma4s(wq.y, cv, acc[q*4+1]);
      acc[q*4+2] = fma4s(wq.z, cv, acc[q*4+2]);
      acc[q*4+3] = fma4s(wq.w, cv, acc[q*4+3]);
    }
  }

  float* ob = out + ((size_t)b * COUT + og) * NPIX + px;
#pragma unroll
  for (int i = 0; i < 16; ++i) *(float4*)(ob + (size_t)i * NPIX) = acc[i];
}

// ---------------------------------------------------------------------------
extern "C" void kernel_launch(void* const* d_in, const int* in_sizes, int n_in,
                              void* d_out, int out_size, void* d_ws, size_t ws_size,
                              hipStream_t stream)
{
  const float* x  = (const float*)d_in[0];
  const float* wr = (const float*)d_in[1];
  const float* wp = (const float*)d_in[2];
  float* out = (float*)d_out;

  // ws layout (floats):
  //   wrT[16384] | wpT[32768] | [CG] cnorm[8*4096] [CG] |
  //   feat[8*64*4096] (c-major) | corr[8*64*4096]
  // feat's +-195 halo reads land in cnorm tail guard (zeroed) / corr (finite).
  // total = 4,243,968 floats ~= 16.2 MiB
  float* ws = (float*)d_ws;
  float* wrT    = ws;
  float* wpT    = wrT + CR * CIN;
  float* cnormG = wpT + COUT * CR;          // guarded region base
  float* cnorm  = cnormG + CG;
  float* feat   = cnorm + NB * NPIX + CG;
  float* corr   = feat + (size_t)NB * CR * NPIX;

  hipLaunchKernelGGL(k0_prep,   dim3(194),  dim3(256), 0, stream, wr, wp, wrT, wpT, cnormG);
  hipLaunchKernelGGL(k1_reduce, dim3(256),  dim3(512), 0, stream, x, wrT, feat, cnorm);
  hipLaunchKernelGGL(k2_corr,   dim3(512),  dim3(256), 0, stream, feat, cnorm, corr);
  hipLaunchKernelGGL(k3_proj,   dim3(1024), dim3(256), 0, stream, corr, wpT, out);
}

// Round 8
// 114.324 us; speedup vs baseline: 1.8315x; 1.0511x over previous
//
#include <hip/hip_runtime.h>

#define NPIX 4096
#define CIN  256
#define CR   64
#define COUT 512
#define NB   8
#define CG   256     // cnorm guard floats each side (covers +-195)

__device__ __forceinline__ float4 fma4s(float s, float4 v, float4 a) {
  a.x = fmaf(s, v.x, a.x);
  a.y = fmaf(s, v.y, a.y);
  a.z = fmaf(s, v.z, a.z);
  a.w = fmaf(s, v.w, a.w);
  return a;
}

// ---------------------------------------------------------------------------
// K0: transpose weights (wrT[c][o], wpT[c][o]) + zero cnorm guard zones.
// grid = 194 blocks * 256 = 49664 = 16384 + 32768 + 2*CG exactly.
// ---------------------------------------------------------------------------
__global__ __launch_bounds__(256) void k0_prep(
    const float* __restrict__ wr, const float* __restrict__ wp,
    float* __restrict__ wrT, float* __restrict__ wpT,
    float* __restrict__ cnormG)
{
  const int tid = blockIdx.x * 256 + threadIdx.x;
  if (tid < CR * CIN) {                       // wr[64][256] -> wrT[256][64]
    const int o = tid >> 8, c = tid & 255;
    wrT[c * CR + o] = wr[tid];
  } else if (tid < CR * CIN + COUT * CR) {    // wp[512][64] -> wpT[64][512]
    const int t = tid - CR * CIN;
    const int o = t >> 6, c = t & 63;
    wpT[c * COUT + o] = wp[t];
  } else {
    const int gi = tid - (CR * CIN + COUT * CR);
    if (gi < CG) cnormG[gi] = 0.f;                              // head guard
    else         cnormG[CG + NB * NPIX + (gi - CG)] = 0.f;      // tail guard
  }
}

// ---------------------------------------------------------------------------
// K1: feat[b,c,px] = sum_k wrT[k][c] * x[b,k,px] (c-major);
//     cnorm[b,px] = sqrt(sum_c feat^2).
// 512 blocks x 512 thr = 4096 waves (4/SIMD). Block = (b, 64-px segment).
// Wave g owns out-channels [g*8, g*8+8); thread = 8 outs x 1 px.
// Weight addresses wave-uniform -> s_load. LDS reduce for cnorm.
// ---------------------------------------------------------------------------
__global__ __launch_bounds__(512) void k1_reduce(
    const float* __restrict__ x, const float* __restrict__ wrT,
    float* __restrict__ feat, float* __restrict__ cnorm)
{
  const int blk = blockIdx.x;             // 512 blocks
  const int b = blk >> 6, seg = blk & 63;
  const int lane = threadIdx.x & 63;
  const int g = __builtin_amdgcn_readfirstlane((int)threadIdx.x >> 6);  // 0..7
  const int px = seg * 64 + lane;

  const float* xp = x + (size_t)b * CIN * NPIX + px;
  const float* wb = wrT + g * 8;

  float a[8];
#pragma unroll
  for (int i = 0; i < 8; ++i) a[i] = 0.f;

#pragma unroll 8
  for (int k = 0; k < CIN; ++k) {
    const float xv = xp[(size_t)k * NPIX];
    const float4 w0 = *(const float4*)(wb + k * CR);      // uniform -> s_load
    const float4 w1 = *(const float4*)(wb + k * CR + 4);
    a[0] = fmaf(w0.x, xv, a[0]);
    a[1] = fmaf(w0.y, xv, a[1]);
    a[2] = fmaf(w0.z, xv, a[2]);
    a[3] = fmaf(w0.w, xv, a[3]);
    a[4] = fmaf(w1.x, xv, a[4]);
    a[5] = fmaf(w1.y, xv, a[5]);
    a[6] = fmaf(w1.z, xv, a[6]);
    a[7] = fmaf(w1.w, xv, a[7]);
  }

  // c-major store: feat[b][c][px]
#pragma unroll
  for (int i = 0; i < 8; ++i)
    feat[((size_t)b * CR + g * 8 + i) * NPIX + px] = a[i];

  float p = 0.f;
#pragma unroll
  for (int i = 0; i < 8; ++i) p = fmaf(a[i], a[i], p);

  __shared__ float lp[8][64];
  lp[g][lane] = p;
  __syncthreads();
  if (threadIdx.x < 64) {
    const int j = threadIdx.x;
    float s = 0.f;
#pragma unroll
    for (int gg = 0; gg < 8; ++gg) s += lp[gg][j];
    cnorm[b * NPIX + seg * 64 + j] = sqrtf(s);
  }
}

// ---------------------------------------------------------------------------
// K2: fused one-pass 49-neighbor cosine-sim softmax attention (c-major feat).
// cosine sim <= 1 -> exp(sim) <= e, no overflow -> NO max pass, NO rescale,
// NO LDS, NO barriers. Block = (b,h) row of 64 px, 512 thr = 8 waves;
// 8 lanes per px, each owning 8 channels; dot combined via shfl_xor(1,2,4).
// 512 blocks x 8 waves = 4096 waves (4/SIMD). XCD mapping b=blk&7 keeps
// feat[b] (1 MB) resident in one XCD's L2.
// OOB k: sim select-masked to 0 (p=1 counts in l, matching zero-pad
// reference) and value-masked out of acc; guard reads are finite.
// ---------------------------------------------------------------------------
__global__ __launch_bounds__(512) void k2_corr(
    const float* __restrict__ feat, const float* __restrict__ cnorm,
    float* __restrict__ corr)
{
  const int blk = blockIdx.x;          // 512
  const int b = blk & 7, h = blk >> 3; // XCD-aware: xcd = blk % 8 = b
  const int t = threadIdx.x;
  const int w = t >> 3;                // px col 0..63
  const int cb = (t & 7) * 8;          // channel base for this lane
  const int px = h * 64 + w;
  const int gpx = b * NPIX + px;

  const float* fpx = feat + (size_t)b * CR * NPIX + (size_t)cb * NPIX + px;
  const float cnc = cnorm[gpx];

  float fc[8];
#pragma unroll
  for (int i = 0; i < 8; ++i) fc[i] = fpx[i * NPIX];

  float acc[8];
#pragma unroll
  for (int i = 0; i < 8; ++i) acc[i] = 0.f;
  float l = 0.f;

  for (int dy = -3; dy <= 3; ++dy) {
    const bool rowok = (unsigned)(h + dy) < 64u;
#pragma unroll
    for (int dx = -3; dx <= 3; ++dx) {
      const int koff = dy * 64 + dx;
      float nf[8];
#pragma unroll
      for (int i = 0; i < 8; ++i) nf[i] = fpx[i * NPIX + koff];
      float d = 0.f;
#pragma unroll
      for (int i = 0; i < 8; ++i) d = fmaf(fc[i], nf[i], d);
      d += __shfl_xor(d, 1);
      d += __shfl_xor(d, 2);
      d += __shfl_xor(d, 4);
      const float cnk = cnorm[gpx + koff];
      float sim = d * __builtin_amdgcn_rcpf(fmaxf(cnc * cnk, 1e-8f));
      const bool valid = rowok & ((unsigned)(w + dx) < 64u);
      sim = valid ? sim : 0.f;         // select: NaN/Inf-safe
      const float p = __expf(sim);     // sim <= 1 -> p <= e
      l += p;
      const float pv = valid ? p : 0.f;  // zero-pad patches contribute 0
#pragma unroll
      for (int i = 0; i < 8; ++i) acc[i] = fmaf(pv, nf[i], acc[i]);
    }
  }

  const float inv = __builtin_amdgcn_rcpf(l);
  float* cp = corr + (size_t)b * CR * NPIX + (size_t)cb * NPIX + px;
#pragma unroll
  for (int i = 0; i < 8; ++i) cp[i * NPIX] = acc[i] * inv;
}

// ---------------------------------------------------------------------------
// K3: out[b,o,px] = sum_k wpT[k][o] * corr[b,k,px].
// Thread = 16 outs x 4 px (float4). 1024 blocks x 256 thr. Block decode puts
// the 8 mt-blocks sharing a (b,nt) corr tile on one XCD (blk%8 = nt%8... mt).
// ---------------------------------------------------------------------------
__global__ __launch_bounds__(256) void k3_proj(
    const float* __restrict__ corr, const float* __restrict__ wpT,
    float* __restrict__ out)
{
  const int blk = blockIdx.x;   // 1024: mt(3b) | b(3b) | nt(4b)
  const int mt = blk >> 7, b = (blk >> 4) & 7, nt = blk & 15;
  const int lane = threadIdx.x & 63;
  const int g = __builtin_amdgcn_readfirstlane((int)threadIdx.x >> 6);
  const int px = nt * 256 + lane * 4;
  const int og = mt * 64 + g * 16;

  const float* cp = corr + (size_t)b * CR * NPIX + px;
  const float* wb = wpT + og;

  float4 acc[16];
#pragma unroll
  for (int i = 0; i < 16; ++i) acc[i] = make_float4(0.f, 0.f, 0.f, 0.f);

#pragma unroll 2
  for (int k = 0; k < CR; ++k) {
    const float4 cv = *(const float4*)(cp + (size_t)k * NPIX);
    const float4* wk = (const float4*)(wb + k * COUT);
#pragma unroll
    for (int q = 0; q < 4; ++q) {
      const float4 wq = wk[q];
      acc[q*4+0] = fma4s(wq.x, cv, acc[q*4+0]);
      acc[q*4+1] = fma4s(wq.y, cv, acc[q*4+1]);
      acc[q*4+2] = fma4s(wq.z, cv, acc[q*4+2]);
      acc[q*4+3] = fma4s(wq.w, cv, acc[q*4+3]);
    }
  }

  float* ob = out + ((size_t)b * COUT + og) * NPIX + px;
#pragma unroll
  for (int i = 0; i < 16; ++i) *(float4*)(ob + (size_t)i * NPIX) = acc[i];
}

// ---------------------------------------------------------------------------
extern "C" void kernel_launch(void* const* d_in, const int* in_sizes, int n_in,
                              void* d_out, int out_size, void* d_ws, size_t ws_size,
                              hipStream_t stream)
{
  const float* x  = (const float*)d_in[0];
  const float* wr = (const float*)d_in[1];
  const float* wp = (const float*)d_in[2];
  float* out = (float*)d_out;

  // ws layout (floats):
  //   wrT[16384] | wpT[32768] | [CG] cnorm[8*4096] [CG] |
  //   feat[8*64*4096] (c-major) | corr[8*64*4096]
  // feat's +-195 halo reads land in cnorm tail guard (zeroed) / corr (finite).
  float* ws = (float*)d_ws;
  float* wrT    = ws;
  float* wpT    = wrT + CR * CIN;
  float* cnormG = wpT + COUT * CR;          // guarded region base
  float* cnorm  = cnormG + CG;
  float* feat   = cnorm + NB * NPIX + CG;
  float* corr   = feat + (size_t)NB * CR * NPIX;

  hipLaunchKernelGGL(k0_prep,   dim3(194),  dim3(256), 0, stream, wr, wp, wrT, wpT, cnormG);
  hipLaunchKernelGGL(k1_reduce, dim3(512),  dim3(512), 0, stream, x, wrT, feat, cnorm);
  hipLaunchKernelGGL(k2_corr,   dim3(512),  dim3(512), 0, stream, feat, cnorm, corr);
  hipLaunchKernelGGL(k3_proj,   dim3(1024), dim3(256), 0, stream, corr, wpT, out);
}

// Round 9
// 90.952 us; speedup vs baseline: 2.3021x; 1.2570x over previous
//
#include <hip/hip_runtime.h>

#define NPIX 4096
#define CIN  256
#define CR   64
#define COUT 512
#define NB   8
#define CG   256     // cnorm guard floats each side (covers +-195)

__device__ __forceinline__ float4 fma4s(float s, float4 v, float4 a) {
  a.x = fmaf(s, v.x, a.x);
  a.y = fmaf(s, v.y, a.y);
  a.z = fmaf(s, v.z, a.z);
  a.w = fmaf(s, v.w, a.w);
  return a;
}

// ---------------------------------------------------------------------------
// K0: transpose weights (wrT[c][o], wpT[c][o]) + zero cnorm guard zones.
// grid = 194 blocks * 256 = 49664 = 16384 + 32768 + 2*CG exactly.
// ---------------------------------------------------------------------------
__global__ __launch_bounds__(256) void k0_prep(
    const float* __restrict__ wr, const float* __restrict__ wp,
    float* __restrict__ wrT, float* __restrict__ wpT,
    float* __restrict__ cnormG)
{
  const int tid = blockIdx.x * 256 + threadIdx.x;
  if (tid < CR * CIN) {                       // wr[64][256] -> wrT[256][64]
    const int o = tid >> 8, c = tid & 255;
    wrT[c * CR + o] = wr[tid];
  } else if (tid < CR * CIN + COUT * CR) {    // wp[512][64] -> wpT[64][512]
    const int t = tid - CR * CIN;
    const int o = t >> 6, c = t & 63;
    wpT[c * COUT + o] = wp[t];
  } else {
    const int gi = tid - (CR * CIN + COUT * CR);
    if (gi < CG) cnormG[gi] = 0.f;                              // head guard
    else         cnormG[CG + NB * NPIX + (gi - CG)] = 0.f;      // tail guard
  }
}

// ---------------------------------------------------------------------------
// K1: feat[b,c,px] = sum_k wrT[k][c] * x[b,k,px] (c-major);
//     cnorm[b,px] = sqrt(sum_c feat^2).
// 512 blocks x 512 thr = 4096 waves. Wave g owns out-channels [g*8, g*8+8).
// ---------------------------------------------------------------------------
__global__ __launch_bounds__(512) void k1_reduce(
    const float* __restrict__ x, const float* __restrict__ wrT,
    float* __restrict__ feat, float* __restrict__ cnorm)
{
  const int blk = blockIdx.x;             // 512 blocks
  const int b = blk >> 6, seg = blk & 63;
  const int lane = threadIdx.x & 63;
  const int g = __builtin_amdgcn_readfirstlane((int)threadIdx.x >> 6);  // 0..7
  const int px = seg * 64 + lane;

  const float* xp = x + (size_t)b * CIN * NPIX + px;
  const float* wb = wrT + g * 8;

  float a[8];
#pragma unroll
  for (int i = 0; i < 8; ++i) a[i] = 0.f;

#pragma unroll 8
  for (int k = 0; k < CIN; ++k) {
    const float xv = xp[(size_t)k * NPIX];
    const float4 w0 = *(const float4*)(wb + k * CR);      // uniform -> s_load
    const float4 w1 = *(const float4*)(wb + k * CR + 4);
    a[0] = fmaf(w0.x, xv, a[0]);
    a[1] = fmaf(w0.y, xv, a[1]);
    a[2] = fmaf(w0.z, xv, a[2]);
    a[3] = fmaf(w0.w, xv, a[3]);
    a[4] = fmaf(w1.x, xv, a[4]);
    a[5] = fmaf(w1.y, xv, a[5]);
    a[6] = fmaf(w1.z, xv, a[6]);
    a[7] = fmaf(w1.w, xv, a[7]);
  }

#pragma unroll
  for (int i = 0; i < 8; ++i)
    feat[((size_t)b * CR + g * 8 + i) * NPIX + px] = a[i];

  float p = 0.f;
#pragma unroll
  for (int i = 0; i < 8; ++i) p = fmaf(a[i], a[i], p);

  __shared__ float lp[8][64];
  lp[g][lane] = p;
  __syncthreads();
  if (threadIdx.x < 64) {
    const int j = threadIdx.x;
    float s = 0.f;
#pragma unroll
    for (int gg = 0; gg < 8; ++gg) s += lp[gg][j];
    cnorm[b * NPIX + seg * 64 + j] = sqrtf(s);
  }
}

// ---------------------------------------------------------------------------
// K2: fused one-pass 49-neighbor cosine-sim softmax attention, LDS-staged.
// Block = (b,h) row, 512 thr (8 waves); lane = (px w = t>>3, 8 channels
// cb = (t&7)*8). Per valid neighbor row (dy phase): stage 64ch x 72px tile
// (px h*64-4 .. +67) into double-buffered LDS; next row's stage issues BEFORE
// current row's compute so its latency hides under the math; one barrier per
// phase. Reads fs[cb+i][w+4+dx] at stride 73 -> 2-way bank alias (free).
// cosine sim <= 1 -> exp(sim) <= e -> no max pass/rescale. OOB rows: skipped,
// l += 7 (exp(0)=1 each). OOB cols: overhang values finite (guards/adjacent
// planes), select-masked before use (NaN-safe). XCD map b=blk&7 keeps feat[b]
// (1 MB) in one XCD's L2 for the staging loads.
// ---------------------------------------------------------------------------
__global__ __launch_bounds__(512) void k2_corr(
    const float* __restrict__ feat, const float* __restrict__ cnorm,
    float* __restrict__ corr)
{
  const int blk = blockIdx.x;          // 512
  const int b = blk & 7, h = blk >> 3; // XCD-aware: xcd = blk % 8 = b
  const int t = threadIdx.x;
  const int w = t >> 3;                // px col 0..63
  const int cb = (t & 7) * 8;          // channel base for this lane
  const int px = h * 64 + w;
  const int gpx = b * NPIX + px;

  const float* fb = feat + (size_t)b * CR * NPIX;

  __shared__ float fs[2][64][73];      // 37376 B, stride-73 rows (2-way free)

  // staging coords for s = t: c = t/72, j = t%72; step s += 512 => j+=8,c+=7,carry
  const int sc0 = t / 72;
  const int sj0 = t - sc0 * 72;

  auto stage = [&](int bufi, int ar) {
    const float* src = fb + ar * 64 - 4;
    int c = sc0, j = sj0;
#pragma unroll
    for (int k = 0; k < 9; ++k) {
      fs[bufi][c][j] = src[(size_t)c * NPIX + j];
      j += 8; c += 7;
      if (j >= 72) { j -= 72; c += 1; }
    }
  };

  const float* fpx = fb + (size_t)cb * NPIX + px;
  float fc[8];
#pragma unroll
  for (int i = 0; i < 8; ++i) fc[i] = fpx[i * NPIX];
  const float cnc = cnorm[gpx];

  float acc[8];
#pragma unroll
  for (int i = 0; i < 8; ++i) acc[i] = 0.f;

  const int lo = (h - 3 < 0) ? 0 : h - 3;
  const int hi = (h + 3 > 63) ? 63 : h + 3;
  float l = 7.0f * (float)(6 - (hi - lo));   // skipped rows: 7 x exp(0)

  int buf = 0;
  stage(0, lo);
  __syncthreads();

  for (int ar = lo; ar <= hi; ++ar) {
    if (ar < hi) stage(buf ^ 1, ar + 1);     // prefetch next row
    const int koff = (ar - h) * 64;
#pragma unroll
    for (int dx = -3; dx <= 3; ++dx) {
      float nf[8];
#pragma unroll
      for (int i = 0; i < 8; ++i) nf[i] = fs[buf][cb + i][w + 4 + dx];
      float d = 0.f;
#pragma unroll
      for (int i = 0; i < 8; ++i) d = fmaf(fc[i], nf[i], d);
      d += __shfl_xor(d, 1);
      d += __shfl_xor(d, 2);
      d += __shfl_xor(d, 4);
      const float cnk = cnorm[gpx + koff + dx];
      float sim = d * __builtin_amdgcn_rcpf(fmaxf(cnc * cnk, 1e-8f));
      const bool valid = (unsigned)(w + dx) < 64u;
      sim = valid ? sim : 0.f;         // select: NaN/Inf-safe
      const float p = __expf(sim);     // sim <= 1 -> p <= e
      l += p;
      const float pv = valid ? p : 0.f;
#pragma unroll
      for (int i = 0; i < 8; ++i) acc[i] = fmaf(pv, nf[i], acc[i]);
    }
    __syncthreads();                   // stage(next) done + fs[buf] free
    buf ^= 1;
  }

  const float inv = __builtin_amdgcn_rcpf(l);
  float* cp = corr + (size_t)b * CR * NPIX + (size_t)cb * NPIX + px;
#pragma unroll
  for (int i = 0; i < 8; ++i) cp[i * NPIX] = acc[i] * inv;
}

// ---------------------------------------------------------------------------
// K3: out[b,o,px] = sum_k wpT[k][o] * corr[b,k,px].
// Thread = 16 outs x 4 px (float4). 1024 blocks x 256 thr.
// ---------------------------------------------------------------------------
__global__ __launch_bounds__(256) void k3_proj(
    const float* __restrict__ corr, const float* __restrict__ wpT,
    float* __restrict__ out)
{
  const int blk = blockIdx.x;   // 1024: mt(3b) | b(3b) | nt(4b)
  const int mt = blk >> 7, b = (blk >> 4) & 7, nt = blk & 15;
  const int lane = threadIdx.x & 63;
  const int g = __builtin_amdgcn_readfirstlane((int)threadIdx.x >> 6);
  const int px = nt * 256 + lane * 4;
  const int og = mt * 64 + g * 16;

  const float* cp = corr + (size_t)b * CR * NPIX + px;
  const float* wb = wpT + og;

  float4 acc[16];
#pragma unroll
  for (int i = 0; i < 16; ++i) acc[i] = make_float4(0.f, 0.f, 0.f, 0.f);

#pragma unroll 2
  for (int k = 0; k < CR; ++k) {
    const float4 cv = *(const float4*)(cp + (size_t)k * NPIX);
    const float4* wk = (const float4*)(wb + k * COUT);
#pragma unroll
    for (int q = 0; q < 4; ++q) {
      const float4 wq = wk[q];
      acc[q*4+0] = fma4s(wq.x, cv, acc[q*4+0]);
      acc[q*4+1] = fma4s(wq.y, cv, acc[q*4+1]);
      acc[q*4+2] = fma4s(wq.z, cv, acc[q*4+2]);
      acc[q*4+3] = fma4s(wq.w, cv, acc[q*4+3]);
    }
  }

  float* ob = out + ((size_t)b * COUT + og) * NPIX + px;
#pragma unroll
  for (int i = 0; i < 16; ++i) *(float4*)(ob + (size_t)i * NPIX) = acc[i];
}

// ---------------------------------------------------------------------------
extern "C" void kernel_launch(void* const* d_in, const int* in_sizes, int n_in,
                              void* d_out, int out_size, void* d_ws, size_t ws_size,
                              hipStream_t stream)
{
  const float* x  = (const float*)d_in[0];
  const float* wr = (const float*)d_in[1];
  const float* wp = (const float*)d_in[2];
  float* out = (float*)d_out;

  // ws layout (floats):
  //   wrT[16384] | wpT[32768] | [CG] cnorm[8*4096] [CG] |
  //   feat[8*64*4096] (c-major) | corr[8*64*4096]
  // feat's +-4 px staging overhang lands in cnorm tail guard / adjacent
  // planes / corr (all finite, masked before use).
  float* ws = (float*)d_ws;
  float* wrT    = ws;
  float* wpT    = wrT + CR * CIN;
  float* cnormG = wpT + COUT * CR;          // guarded region base
  float* cnorm  = cnormG + CG;
  float* feat   = cnorm + NB * NPIX + CG;
  float* corr   = feat + (size_t)NB * CR * NPIX;

  hipLaunchKernelGGL(k0_prep,   dim3(194),  dim3(256), 0, stream, wr, wp, wrT, wpT, cnormG);
  hipLaunchKernelGGL(k1_reduce, dim3(512),  dim3(512), 0, stream, x, wrT, feat, cnorm);
  hipLaunchKernelGGL(k2_corr,   dim3(512),  dim3(512), 0, stream, feat, cnorm, corr);
  hipLaunchKernelGGL(k3_proj,   dim3(1024), dim3(256), 0, stream, corr, wpT, out);
}

// Round 10
// 79.781 us; speedup vs baseline: 2.6244x; 1.1400x over previous
//
#include <hip/hip_runtime.h>

#define NPIX 4096
#define CIN  256
#define CR   64
#define COUT 512
#define NB   8
#define CG   256     // cnorm guard floats each side (covers +-195)
#define FT   128     // feat tail guard (staging overhang +67)

// ---------------------------------------------------------------------------
// K0: transpose weights (wrT[c][o], wpT[c][o]) + zero guard zones.
// 195 blocks * 256 covers 16384 + 32768 + 2*CG + FT = 49792 (bounds-checked).
// ---------------------------------------------------------------------------
__global__ __launch_bounds__(256) void k0_prep(
    const float* __restrict__ wr, const float* __restrict__ wp,
    float* __restrict__ wrT, float* __restrict__ wpT,
    float* __restrict__ cnormG, float* __restrict__ featTail)
{
  const int tid = blockIdx.x * 256 + threadIdx.x;
  if (tid < CR * CIN) {                       // wr[64][256] -> wrT[256][64]
    const int o = tid >> 8, c = tid & 255;
    wrT[c * CR + o] = wr[tid];
  } else if (tid < CR * CIN + COUT * CR) {    // wp[512][64] -> wpT[64][512]
    const int t = tid - CR * CIN;
    const int o = t >> 6, c = t & 63;
    wpT[c * COUT + o] = wp[t];
  } else {
    const int gi = tid - (CR * CIN + COUT * CR);
    if (gi < CG)            cnormG[gi] = 0.f;                        // head
    else if (gi < 2 * CG)   cnormG[CG + NB * NPIX + (gi - CG)] = 0.f; // tail
    else if (gi < 2 * CG + FT) featTail[gi - 2 * CG] = 0.f;          // feat tail
  }
}

// ---------------------------------------------------------------------------
// K1: feat[b,c,px] = sum_k wrT[k][c] * x[b,k,px] (c-major);
//     cnorm[b,px] = sqrt(sum_c feat^2).
// 512 blocks x 512 thr = 4096 waves. Wave g owns out-channels [g*8, g*8+8).
// ---------------------------------------------------------------------------
__global__ __launch_bounds__(512) void k1_reduce(
    const float* __restrict__ x, const float* __restrict__ wrT,
    float* __restrict__ feat, float* __restrict__ cnorm)
{
  const int blk = blockIdx.x;             // 512 blocks
  const int b = blk >> 6, seg = blk & 63;
  const int lane = threadIdx.x & 63;
  const int g = __builtin_amdgcn_readfirstlane((int)threadIdx.x >> 6);  // 0..7
  const int px = seg * 64 + lane;

  const float* xp = x + (size_t)b * CIN * NPIX + px;
  const float* wb = wrT + g * 8;

  float a[8];
#pragma unroll
  for (int i = 0; i < 8; ++i) a[i] = 0.f;

#pragma unroll 8
  for (int k = 0; k < CIN; ++k) {
    const float xv = xp[(size_t)k * NPIX];
    const float4 w0 = *(const float4*)(wb + k * CR);      // uniform -> s_load
    const float4 w1 = *(const float4*)(wb + k * CR + 4);
    a[0] = fmaf(w0.x, xv, a[0]);
    a[1] = fmaf(w0.y, xv, a[1]);
    a[2] = fmaf(w0.z, xv, a[2]);
    a[3] = fmaf(w0.w, xv, a[3]);
    a[4] = fmaf(w1.x, xv, a[4]);
    a[5] = fmaf(w1.y, xv, a[5]);
    a[6] = fmaf(w1.z, xv, a[6]);
    a[7] = fmaf(w1.w, xv, a[7]);
  }

#pragma unroll
  for (int i = 0; i < 8; ++i)
    feat[((size_t)b * CR + g * 8 + i) * NPIX + px] = a[i];

  float p = 0.f;
#pragma unroll
  for (int i = 0; i < 8; ++i) p = fmaf(a[i], a[i], p);

  __shared__ float lp[8][64];
  lp[g][lane] = p;
  __syncthreads();
  if (threadIdx.x < 64) {
    const int j = threadIdx.x;
    float s = 0.f;
#pragma unroll
    for (int gg = 0; gg < 8; ++gg) s += lp[gg][j];
    cnorm[b * NPIX + seg * 64 + j] = sqrtf(s);
  }
}

// ---------------------------------------------------------------------------
// K23: fused correlation-softmax-attention + projection.
// Block = (b,h) row of 64 px, 512 thr (8 waves). XCD map b=blk&7.
//
// Phase A (attention): fs[px j][ch] staged per neighbor row (double-buffered,
// [72][68] stride -> balanced banks for both the transposed scalar writes and
// the 2x ds_read_b128 per (px, neighbor)). Lane = (w=t>>3, 8 channels
// cb=(t&7)*8); dot via shfl_xor(1,2,4). cosine sim <= 1 -> exp(sim) <= e ->
// one-pass softmax, no max/rescale. OOB rows skipped (l += 7, exp(0)=1 each);
// OOB cols select-masked (overhang reads finite via guards).
//
// Phase B (proj): normalized corr -> corrS[ch][px 65] (conflict-free W+R),
// wave g computes outs [g*64,g*64+64) x 64 px; weights wave-uniform s_loads.
// corr never touches global memory.
// ---------------------------------------------------------------------------
__global__ __launch_bounds__(512, 4) void k23_fused(
    const float* __restrict__ feat, const float* __restrict__ cnorm,
    const float* __restrict__ wpT, float* __restrict__ out)
{
  const int blk = blockIdx.x;          // 512
  const int b = blk & 7, h = blk >> 3; // XCD-aware: xcd = blk % 8 = b
  const int t = threadIdx.x;
  const int lane = t & 63;
  const int g = __builtin_amdgcn_readfirstlane((int)t >> 6);  // 0..7
  const int w = t >> 3;                // px col 0..63
  const int cb = (t & 7) * 8;          // channel base for this lane
  const int px = h * 64 + w;
  const int gpx = b * NPIX + px;

  const float* fb = feat + (size_t)b * CR * NPIX;

  __shared__ float fs[2][72][68];      // 39168 B: [px j][ch], j = imgcol+4
  __shared__ float corrS[64][65];      // 16640 B: [ch][px]

  auto stage = [&](int bufi, int ar) {
    const float* src = fb + ar * 64 - 4;   // head overhang -> cnorm tail guard
#pragma unroll
    for (int cc = 0; cc < 8; ++cc) {
      const int c = g * 8 + cc;
      fs[bufi][lane][c] = src[(size_t)c * NPIX + lane];          // j = lane
    }
    if (lane < 8) {
#pragma unroll
      for (int cc = 0; cc < 8; ++cc) {
        const int c = g * 8 + cc;
        fs[bufi][64 + lane][c] = src[(size_t)c * NPIX + 64 + lane];
      }
    }
  };

  const float* fpx = fb + (size_t)cb * NPIX + px;
  float fc[8];
#pragma unroll
  for (int i = 0; i < 8; ++i) fc[i] = fpx[i * NPIX];
  const float cnc = cnorm[gpx];

  float acc[8];
#pragma unroll
  for (int i = 0; i < 8; ++i) acc[i] = 0.f;

  const int lo = (h - 3 < 0) ? 0 : h - 3;
  const int hi = (h + 3 > 63) ? 63 : h + 3;
  float l = 7.0f * (float)(6 - (hi - lo));   // skipped rows: 7 x exp(0)

  int buf = 0;
  stage(0, lo);
  __syncthreads();

  for (int ar = lo; ar <= hi; ++ar) {
    if (ar < hi) stage(buf ^ 1, ar + 1);     // prefetch next row
    const int koff = (ar - h) * 64;
#pragma unroll
    for (int dx = -3; dx <= 3; ++dx) {
      const int j = w + 4 + dx;
      const float4 nv0 = *(const float4*)&fs[buf][j][cb];
      const float4 nv1 = *(const float4*)&fs[buf][j][cb + 4];
      float d = fmaf(fc[0], nv0.x,
                fmaf(fc[1], nv0.y,
                fmaf(fc[2], nv0.z,
                fmaf(fc[3], nv0.w,
                fmaf(fc[4], nv1.x,
                fmaf(fc[5], nv1.y,
                fmaf(fc[6], nv1.z, fc[7] * nv1.w)))))));
      d += __shfl_xor(d, 1);
      d += __shfl_xor(d, 2);
      d += __shfl_xor(d, 4);
      const float cnk = cnorm[gpx + koff + dx];
      float sim = d * __builtin_amdgcn_rcpf(fmaxf(cnc * cnk, 1e-8f));
      const bool valid = (unsigned)(w + dx) < 64u;
      sim = valid ? sim : 0.f;         // select: NaN/Inf-safe
      const float p = __expf(sim);     // sim <= 1 -> p <= e
      l += p;
      const float pv = valid ? p : 0.f;
      acc[0] = fmaf(pv, nv0.x, acc[0]);
      acc[1] = fmaf(pv, nv0.y, acc[1]);
      acc[2] = fmaf(pv, nv0.z, acc[2]);
      acc[3] = fmaf(pv, nv0.w, acc[3]);
      acc[4] = fmaf(pv, nv1.x, acc[4]);
      acc[5] = fmaf(pv, nv1.y, acc[5]);
      acc[6] = fmaf(pv, nv1.z, acc[6]);
      acc[7] = fmaf(pv, nv1.w, acc[7]);
    }
    if (ar < hi) __syncthreads();      // stage(next) complete
    buf ^= 1;
  }

  // normalized corr row -> LDS (banks: (8q+i+w) spread, 2-way = free)
  const float inv = __builtin_amdgcn_rcpf(l);
#pragma unroll
  for (int i = 0; i < 8; ++i) corrS[cb + i][w] = acc[i] * inv;
  __syncthreads();

  // ---- Phase B: proj. Wave g -> outs [g*64, g*64+64), lane -> px column.
  float accB[64];
#pragma unroll
  for (int i = 0; i < 64; ++i) accB[i] = 0.f;

  const float* wbase = wpT + g * 64;
#pragma unroll 2
  for (int k = 0; k < CR; ++k) {
    const float cv = corrS[k][lane];                 // conflict-free
    const float4* wk4 = (const float4*)(wbase + k * COUT);  // uniform s_load
#pragma unroll
    for (int i4 = 0; i4 < 16; ++i4) {
      const float4 wq = wk4[i4];
      accB[i4 * 4 + 0] = fmaf(wq.x, cv, accB[i4 * 4 + 0]);
      accB[i4 * 4 + 1] = fmaf(wq.y, cv, accB[i4 * 4 + 1]);
      accB[i4 * 4 + 2] = fmaf(wq.z, cv, accB[i4 * 4 + 2]);
      accB[i4 * 4 + 3] = fmaf(wq.w, cv, accB[i4 * 4 + 3]);
    }
  }

  float* ob = out + ((size_t)b * COUT + g * 64) * NPIX + h * 64 + lane;
#pragma unroll
  for (int i = 0; i < 64; ++i) ob[(size_t)i * NPIX] = accB[i];
}

// ---------------------------------------------------------------------------
extern "C" void kernel_launch(void* const* d_in, const int* in_sizes, int n_in,
                              void* d_out, int out_size, void* d_ws, size_t ws_size,
                              hipStream_t stream)
{
  const float* x  = (const float*)d_in[0];
  const float* wr = (const float*)d_in[1];
  const float* wp = (const float*)d_in[2];
  float* out = (float*)d_out;

  // ws layout (floats):
  //   wrT[16384] | wpT[32768] | [CG] cnorm[8*4096] [CG] |
  //   feat[8*64*4096] (c-major) | [FT tail guard]
  // staging overhang (-4 / +67) lands in cnorm tail guard / feat tail guard.
  float* ws = (float*)d_ws;
  float* wrT      = ws;
  float* wpT      = wrT + CR * CIN;
  float* cnormG   = wpT + COUT * CR;        // guarded region base
  float* cnorm    = cnormG + CG;
  float* feat     = cnorm + NB * NPIX + CG;
  float* featTail = feat + (size_t)NB * CR * NPIX;

  hipLaunchKernelGGL(k0_prep,   dim3(195), dim3(256), 0, stream, wr, wp, wrT, wpT, cnormG, featTail);
  hipLaunchKernelGGL(k1_reduce, dim3(512), dim3(512), 0, stream, x, wrT, feat, cnorm);
  hipLaunchKernelGGL(k23_fused, dim3(512), dim3(512), 0, stream, feat, cnorm, wpT, out);
}

// Round 11
// 79.169 us; speedup vs baseline: 2.6447x; 1.0077x over previous
//
#include <hip/hip_runtime.h>

#define NPIX 4096
#define CIN  256
#define CR   64
#define COUT 512
#define NB   8
#define CG   256     // cnorm guard floats each side
#define FT   128     // feat tail guard (staging overhang +3)

// ---------------------------------------------------------------------------
// K0: transpose weights (wrT[c][o], wpT[c][o]) + zero guard zones.
// ---------------------------------------------------------------------------
__global__ __launch_bounds__(256) void k0_prep(
    const float* __restrict__ wr, const float* __restrict__ wp,
    float* __restrict__ wrT, float* __restrict__ wpT,
    float* __restrict__ cnormG, float* __restrict__ featTail)
{
  const int tid = blockIdx.x * 256 + threadIdx.x;
  if (tid < CR * CIN) {                       // wr[64][256] -> wrT[256][64]
    const int o = tid >> 8, c = tid & 255;
    wrT[c * CR + o] = wr[tid];
  } else if (tid < CR * CIN + COUT * CR) {    // wp[512][64] -> wpT[64][512]
    const int t = tid - CR * CIN;
    const int o = t >> 6, c = t & 63;
    wpT[c * COUT + o] = wp[t];
  } else {
    const int gi = tid - (CR * CIN + COUT * CR);
    if (gi < CG)               cnormG[gi] = 0.f;                         // head
    else if (gi < 2 * CG)      cnormG[CG + NB * NPIX + (gi - CG)] = 0.f; // tail
    else if (gi < 2 * CG + FT) featTail[gi - 2 * CG] = 0.f;              // feat tail
  }
}

// ---------------------------------------------------------------------------
// K1: feat[b,c,px] = sum_k wrT[k][c] * x[b,k,px] (c-major);
//     cnorm[b,px] = sqrt(sum_c feat^2).
// 512 blocks x 512 thr. Wave g owns out-channels [g*8, g*8+8).
// ---------------------------------------------------------------------------
__global__ __launch_bounds__(512) void k1_reduce(
    const float* __restrict__ x, const float* __restrict__ wrT,
    float* __restrict__ feat, float* __restrict__ cnorm)
{
  const int blk = blockIdx.x;             // 512 blocks
  const int b = blk >> 6, seg = blk & 63;
  const int lane = threadIdx.x & 63;
  const int g = __builtin_amdgcn_readfirstlane((int)threadIdx.x >> 6);  // 0..7
  const int px = seg * 64 + lane;

  const float* xp = x + (size_t)b * CIN * NPIX + px;
  const float* wb = wrT + g * 8;

  float a[8];
#pragma unroll
  for (int i = 0; i < 8; ++i) a[i] = 0.f;

#pragma unroll 8
  for (int k = 0; k < CIN; ++k) {
    const float xv = xp[(size_t)k * NPIX];
    const float4 w0 = *(const float4*)(wb + k * CR);      // uniform -> s_load
    const float4 w1 = *(const float4*)(wb + k * CR + 4);
    a[0] = fmaf(w0.x, xv, a[0]);
    a[1] = fmaf(w0.y, xv, a[1]);
    a[2] = fmaf(w0.z, xv, a[2]);
    a[3] = fmaf(w0.w, xv, a[3]);
    a[4] = fmaf(w1.x, xv, a[4]);
    a[5] = fmaf(w1.y, xv, a[5]);
    a[6] = fmaf(w1.z, xv, a[6]);
    a[7] = fmaf(w1.w, xv, a[7]);
  }

#pragma unroll
  for (int i = 0; i < 8; ++i)
    feat[((size_t)b * CR + g * 8 + i) * NPIX + px] = a[i];

  float p = 0.f;
#pragma unroll
  for (int i = 0; i < 8; ++i) p = fmaf(a[i], a[i], p);

  __shared__ float lp[8][64];
  lp[g][lane] = p;
  __syncthreads();
  if (threadIdx.x < 64) {
    const int j = threadIdx.x;
    float s = 0.f;
#pragma unroll
    for (int gg = 0; gg < 8; ++gg) s += lp[gg][j];
    cnorm[b * NPIX + seg * 64 + j] = sqrtf(s);
  }
}

// ---------------------------------------------------------------------------
// K23: fused correlation-softmax-attention + projection.
// Block = (b,h) row of 64 px, 512 thr (8 waves). XCD map b=blk&7.
//
// Staging (T14 split): per neighbor row, LOAD issues coalesced global reads
// into registers BEFORE compute (latency hides under the 49-neighbor math);
// WRITE packs them as ds_write_b128 into fs[j][c] AFTER compute (8 lanes per
// 4-bank window = b128 volume minimum, no conflict penalty). cnorm row staged
// alongside (cnS). One barrier per row.
//
// Phase A: lane = (w=t>>3 px, cb=(t&7)*8 channels); 2x ds_read_b128 per
// neighbor; dot via shfl_xor(1,2,4); cosine sim <= 1 -> exp(sim) <= e ->
// one-pass softmax (no max/rescale). OOB rows skipped (l += 7); OOB cols
// select-masked (guard reads finite).
//
// Phase B: corr -> corrS[ch][px 65] (2-way/free W, conflict-free R); wave g
// computes outs [g*64,g*64+64) x 64 px, weights wave-uniform s_loads.
// ---------------------------------------------------------------------------
__global__ __launch_bounds__(512, 4) void k23_fused(
    const float* __restrict__ feat, const float* __restrict__ cnorm,
    const float* __restrict__ wpT, float* __restrict__ out)
{
  const int blk = blockIdx.x;          // 512
  const int b = blk & 7, h = blk >> 3; // XCD-aware: xcd = blk % 8 = b
  const int t = threadIdx.x;
  const int lane = t & 63;
  const int g = __builtin_amdgcn_readfirstlane((int)t >> 6);  // 0..7
  const int w = t >> 3;                // px col 0..63
  const int cb = (t & 7) * 8;          // channel base for this lane
  const int px = h * 64 + w;
  const int gpx = b * NPIX + px;

  const float* fb = feat + (size_t)b * CR * NPIX;
  const float* cnb = cnorm + b * NPIX;

  __shared__ float fs[2][72][68];      // 39168 B: [px j][ch]
  __shared__ float cnS[2][80];         // 640 B
  __shared__ float corrS[64][65];      // 16640 B

  // staging registers
  float rA[2][4];                      // main: j=lane, c4 = g*2+k
  float rB[4];                         // tail: t<128 -> j=64+(t>>4), c4=t&15
  float rc = 0.f;                      // cnorm: t<72

  const int jt = 64 + (t >> 4), c4t = t & 15;

  auto LOAD = [&](int ar) {
    const int base = ar * 64 - 4;      // overhang covered by guards
#pragma unroll
    for (int k = 0; k < 2; ++k) {
      const int c4 = g * 2 + k;
#pragma unroll
      for (int q = 0; q < 4; ++q)
        rA[k][q] = fb[(size_t)(c4 * 4 + q) * NPIX + base + lane];  // coalesced
    }
    if (t < 128) {
#pragma unroll
      for (int q = 0; q < 4; ++q)
        rB[q] = fb[(size_t)(c4t * 4 + q) * NPIX + base + jt];
    }
    if (t < 72) rc = cnb[base + t];
  };
  auto WRITE = [&](int bufi) {
#pragma unroll
    for (int k = 0; k < 2; ++k) {
      const int c4 = g * 2 + k;
      *(float4*)&fs[bufi][lane][c4 * 4] =
          make_float4(rA[k][0], rA[k][1], rA[k][2], rA[k][3]);
    }
    if (t < 128)
      *(float4*)&fs[bufi][jt][c4t * 4] = make_float4(rB[0], rB[1], rB[2], rB[3]);
    if (t < 72) cnS[bufi][t] = rc;
  };

  const float* fpx = fb + (size_t)cb * NPIX + px;
  float fc[8];
#pragma unroll
  for (int i = 0; i < 8; ++i) fc[i] = fpx[i * NPIX];
  const float cnc = cnorm[gpx];

  float acc[8];
#pragma unroll
  for (int i = 0; i < 8; ++i) acc[i] = 0.f;

  const int lo = (h - 3 < 0) ? 0 : h - 3;
  const int hi = (h + 3 > 63) ? 63 : h + 3;
  float l = 7.0f * (float)(6 - (hi - lo));   // skipped rows: 7 x exp(0)

  LOAD(lo);
  WRITE(0);
  __syncthreads();

  int buf = 0;
  for (int ar = lo; ar <= hi; ++ar) {
    if (ar < hi) LOAD(ar + 1);               // issue early: hides under compute
    const int koff4 = 4 - h * 64 + 0;        // unused; keep indices simple
    (void)koff4;
#pragma unroll
    for (int dx = -3; dx <= 3; ++dx) {
      const int j = w + 4 + dx;
      const float4 nv0 = *(const float4*)&fs[buf][j][cb];
      const float4 nv1 = *(const float4*)&fs[buf][j][cb + 4];
      float d = fmaf(fc[0], nv0.x,
                fmaf(fc[1], nv0.y,
                fmaf(fc[2], nv0.z,
                fmaf(fc[3], nv0.w,
                fmaf(fc[4], nv1.x,
                fmaf(fc[5], nv1.y,
                fmaf(fc[6], nv1.z, fc[7] * nv1.w)))))));
      d += __shfl_xor(d, 1);
      d += __shfl_xor(d, 2);
      d += __shfl_xor(d, 4);
      const float cnk = cnS[buf][j];
      float sim = d * __builtin_amdgcn_rcpf(fmaxf(cnc * cnk, 1e-8f));
      const bool valid = (unsigned)(w + dx) < 64u;
      sim = valid ? sim : 0.f;         // select: NaN/Inf-safe
      const float p = __expf(sim);     // sim <= 1 -> p <= e
      l += p;
      const float pv = valid ? p : 0.f;
      acc[0] = fmaf(pv, nv0.x, acc[0]);
      acc[1] = fmaf(pv, nv0.y, acc[1]);
      acc[2] = fmaf(pv, nv0.z, acc[2]);
      acc[3] = fmaf(pv, nv0.w, acc[3]);
      acc[4] = fmaf(pv, nv1.x, acc[4]);
      acc[5] = fmaf(pv, nv1.y, acc[5]);
      acc[6] = fmaf(pv, nv1.z, acc[6]);
      acc[7] = fmaf(pv, nv1.w, acc[7]);
    }
    if (ar < hi) WRITE(buf ^ 1);             // vmcnt waits here, not earlier
    __syncthreads();
    buf ^= 1;
  }

  // normalized corr row -> LDS
  const float inv = __builtin_amdgcn_rcpf(l);
#pragma unroll
  for (int i = 0; i < 8; ++i) corrS[cb + i][w] = acc[i] * inv;
  __syncthreads();

  // ---- Phase B: proj. Wave g -> outs [g*64, g*64+64), lane -> px column.
  float accB[64];
#pragma unroll
  for (int i = 0; i < 64; ++i) accB[i] = 0.f;

  const float* wbase = wpT + g * 64;
#pragma unroll 2
  for (int k = 0; k < CR; ++k) {
    const float cv = corrS[k][lane];                 // conflict-free
    const float4* wk4 = (const float4*)(wbase + k * COUT);  // uniform s_load
#pragma unroll
    for (int i4 = 0; i4 < 16; ++i4) {
      const float4 wq = wk4[i4];
      accB[i4 * 4 + 0] = fmaf(wq.x, cv, accB[i4 * 4 + 0]);
      accB[i4 * 4 + 1] = fmaf(wq.y, cv, accB[i4 * 4 + 1]);
      accB[i4 * 4 + 2] = fmaf(wq.z, cv, accB[i4 * 4 + 2]);
      accB[i4 * 4 + 3] = fmaf(wq.w, cv, accB[i4 * 4 + 3]);
    }
  }

  float* ob = out + ((size_t)b * COUT + g * 64) * NPIX + h * 64 + lane;
#pragma unroll
  for (int i = 0; i < 64; ++i) ob[(size_t)i * NPIX] = accB[i];
}

// ---------------------------------------------------------------------------
extern "C" void kernel_launch(void* const* d_in, const int* in_sizes, int n_in,
                              void* d_out, int out_size, void* d_ws, size_t ws_size,
                              hipStream_t stream)
{
  const float* x  = (const float*)d_in[0];
  const float* wr = (const float*)d_in[1];
  const float* wp = (const float*)d_in[2];
  float* out = (float*)d_out;

  // ws layout (floats):
  //   wrT[16384] | wpT[32768] | [CG] cnorm[8*4096] [CG] |
  //   feat[8*64*4096] (c-major) | [FT tail guard]
  // staging overhang (-4 / +3) lands in cnorm tail guard / feat tail guard.
  float* ws = (float*)d_ws;
  float* wrT      = ws;
  float* wpT      = wrT + CR * CIN;
  float* cnormG   = wpT + COUT * CR;        // guarded region base
  float* cnorm    = cnormG + CG;
  float* feat     = cnorm + NB * NPIX + CG;
  float* featTail = feat + (size_t)NB * CR * NPIX;

  hipLaunchKernelGGL(k0_prep,   dim3(195), dim3(256), 0, stream, wr, wp, wrT, wpT, cnormG, featTail);
  hipLaunchKernelGGL(k1_reduce, dim3(512), dim3(512), 0, stream, x, wrT, feat, cnorm);
  hipLaunchKernelGGL(k23_fused, dim3(512), dim3(512), 0, stream, feat, cnorm, wpT, out);
}

// Round 12
// 56.437 us; speedup vs baseline: 3.7100x; 1.4028x over previous
//
#include <hip/hip_runtime.h>
#include <stdint.h>

#define NPIX 4096
#define CIN  256
#define CR   64
#define COUT 512
#define NB   8
#define CG   256     // cnorm guard floats each side
#define FT   128     // feat tail guard

typedef _Float16 half8 __attribute__((ext_vector_type(8)));
typedef float f32x4 __attribute__((ext_vector_type(4)));

// 8-lane sum (groups aligned to 8): quad_perm xor1, xor2, then row_half_mirror
// pulls the other quad's total. Pure VALU - no DS pipe.
__device__ __forceinline__ float dpp8_sum(float d) {
  int y;
  y = __builtin_amdgcn_update_dpp(0, __float_as_int(d), 0xB1, 0xF, 0xF, true);
  d += __int_as_float(y);
  y = __builtin_amdgcn_update_dpp(0, __float_as_int(d), 0x4E, 0xF, 0xF, true);
  d += __int_as_float(y);
  y = __builtin_amdgcn_update_dpp(0, __float_as_int(d), 0x141, 0xF, 0xF, true);
  d += __int_as_float(y);
  return d;
}

// ---------------------------------------------------------------------------
// K0: wrT transpose + wp -> fp16 A-fragments + zero guard zones.
// A-frag layout (16x16x32 f16): frag e=((g*4+ot)*2+kt); lane l holds 8 halfs
// j=0..7 of A[o = g*64+ot*16+(l&15)][k = kt*32+(l>>4)*8+j], stored contiguous
// at wpH[e*512 + l*8 + j]  (16 B per lane -> coalesced wave loads).
// ---------------------------------------------------------------------------
__global__ __launch_bounds__(256) void k0_prep(
    const float* __restrict__ wr, const float* __restrict__ wp,
    float* __restrict__ wrT, _Float16* __restrict__ wpH,
    float* __restrict__ cnormG, float* __restrict__ featTail)
{
  const int tid = blockIdx.x * 256 + threadIdx.x;
  if (tid < CR * CIN) {                       // wr[64][256] -> wrT[256][64]
    const int o = tid >> 8, c = tid & 255;
    wrT[c * CR + o] = wr[tid];
  } else if (tid < CR * CIN + COUT * CR) {    // wp[512][64] -> A-fragments f16
    const int fi = tid - CR * CIN;
    const int j = fi & 7, l = (fi >> 3) & 63;
    const int kt = (fi >> 9) & 1, ot = (fi >> 10) & 3, g = fi >> 12;
    const int o = g * 64 + ot * 16 + (l & 15);
    const int k = kt * 32 + (l >> 4) * 8 + j;
    wpH[fi] = (_Float16)wp[o * CR + k];
  } else {
    const int gi = tid - (CR * CIN + COUT * CR);
    if (gi < CG)               cnormG[gi] = 0.f;                         // head
    else if (gi < 2 * CG)      cnormG[CG + NB * NPIX + (gi - CG)] = 0.f; // tail
    else if (gi < 2 * CG + FT) featTail[gi - 2 * CG] = 0.f;              // feat tail
  }
}

// ---------------------------------------------------------------------------
// K1: feat[b,c,px] = sum_k wrT[k][c] * x[b,k,px] (c-major);
//     cnorm[b,px] = sqrt(sum_c feat^2).  512 blocks x 512 thr.
// ---------------------------------------------------------------------------
__global__ __launch_bounds__(512) void k1_reduce(
    const float* __restrict__ x, const float* __restrict__ wrT,
    float* __restrict__ feat, float* __restrict__ cnorm)
{
  const int blk = blockIdx.x;             // 512 blocks
  const int b = blk >> 6, seg = blk & 63;
  const int lane = threadIdx.x & 63;
  const int g = __builtin_amdgcn_readfirstlane((int)threadIdx.x >> 6);  // 0..7
  const int px = seg * 64 + lane;

  const float* xp = x + (size_t)b * CIN * NPIX + px;
  const float* wb = wrT + g * 8;

  float a[8];
#pragma unroll
  for (int i = 0; i < 8; ++i) a[i] = 0.f;

#pragma unroll 8
  for (int k = 0; k < CIN; ++k) {
    const float xv = xp[(size_t)k * NPIX];
    const float4 w0 = *(const float4*)(wb + k * CR);      // uniform -> s_load
    const float4 w1 = *(const float4*)(wb + k * CR + 4);
    a[0] = fmaf(w0.x, xv, a[0]);
    a[1] = fmaf(w0.y, xv, a[1]);
    a[2] = fmaf(w0.z, xv, a[2]);
    a[3] = fmaf(w0.w, xv, a[3]);
    a[4] = fmaf(w1.x, xv, a[4]);
    a[5] = fmaf(w1.y, xv, a[5]);
    a[6] = fmaf(w1.z, xv, a[6]);
    a[7] = fmaf(w1.w, xv, a[7]);
  }

#pragma unroll
  for (int i = 0; i < 8; ++i)
    feat[((size_t)b * CR + g * 8 + i) * NPIX + px] = a[i];

  float p = 0.f;
#pragma unroll
  for (int i = 0; i < 8; ++i) p = fmaf(a[i], a[i], p);

  __shared__ float lp[8][64];
  lp[g][lane] = p;
  __syncthreads();
  if (threadIdx.x < 64) {
    const int j = threadIdx.x;
    float s = 0.f;
#pragma unroll
    for (int gg = 0; gg < 8; ++gg) s += lp[gg][j];
    cnorm[b * NPIX + seg * 64 + j] = sqrtf(s);
  }
}

// ---------------------------------------------------------------------------
// K23: fused correlation-softmax-attention (fp32) + projection (fp16 MFMA).
// Block = (b,h) row of 64 px, 512 thr (8 waves). XCD map b=blk&7.
//
// Phase A: T14-split staging (LOAD before compute, WRITE after), 8-lane dot
// reduce via DPP (no DS), one-pass softmax (sim<=1 -> exp<=e). OOB rows
// skipped (l+=7); OOB cols select-masked (guard reads finite).
//
// Phase B: corr -> f16 corrH[px][64k] with XOR swizzle byte^=((px&7)<<4);
// wave g computes outs [g*64,g*64+64) x 64 px as 16 tiles of 16x16 via
// 2x mfma_f32_16x16x32_f16 each; A-frags pre-packed by k0 (global, L2-hot).
// C-layout: col=lane&15, row=(lane>>4)*4+reg (m89-verified).
// ---------------------------------------------------------------------------
__global__ __launch_bounds__(512, 4) void k23_fused(
    const float* __restrict__ feat, const float* __restrict__ cnorm,
    const _Float16* __restrict__ wpH, float* __restrict__ out)
{
  const int blk = blockIdx.x;          // 512
  const int b = blk & 7, h = blk >> 3; // XCD-aware: xcd = blk % 8 = b
  const int t = threadIdx.x;
  const int lane = t & 63;
  const int g = __builtin_amdgcn_readfirstlane((int)t >> 6);  // 0..7
  const int w = t >> 3;                // px col 0..63
  const int cb = (t & 7) * 8;          // channel base for this lane
  const int px = h * 64 + w;
  const int gpx = b * NPIX + px;

  const float* fb = feat + (size_t)b * CR * NPIX;
  const float* cnb = cnorm + b * NPIX;

  __shared__ float fs[2][72][68];                  // 39168 B: [px j][ch]
  __shared__ float cnS[2][80];                     // 640 B
  __shared__ __align__(16) _Float16 corrH[4096];   // 8192 B: [px][k] swizzled

  // staging registers
  float rA[2][4];                      // main: j=lane, c4 = g*2+k
  float rB[4];                         // tail: t<128 -> j=64+(t>>4), c4=t&15
  float rc = 0.f;                      // cnorm: t<72
  const int jt = 64 + (t >> 4), c4t = t & 15;

  auto LOAD = [&](int ar) {
    const int base = ar * 64 - 4;      // overhang covered by guards
#pragma unroll
    for (int k = 0; k < 2; ++k) {
      const int c4 = g * 2 + k;
#pragma unroll
      for (int q = 0; q < 4; ++q)
        rA[k][q] = fb[(size_t)(c4 * 4 + q) * NPIX + base + lane];  // coalesced
    }
    if (t < 128) {
#pragma unroll
      for (int q = 0; q < 4; ++q)
        rB[q] = fb[(size_t)(c4t * 4 + q) * NPIX + base + jt];
    }
    if (t < 72) rc = cnb[base + t];
  };
  auto WRITE = [&](int bufi) {
#pragma unroll
    for (int k = 0; k < 2; ++k) {
      const int c4 = g * 2 + k;
      *(float4*)&fs[bufi][lane][c4 * 4] =
          make_float4(rA[k][0], rA[k][1], rA[k][2], rA[k][3]);
    }
    if (t < 128)
      *(float4*)&fs[bufi][jt][c4t * 4] = make_float4(rB[0], rB[1], rB[2], rB[3]);
    if (t < 72) cnS[bufi][t] = rc;
  };

  const float* fpx = fb + (size_t)cb * NPIX + px;
  float fc[8];
#pragma unroll
  for (int i = 0; i < 8; ++i) fc[i] = fpx[i * NPIX];
  const float cnc = cnorm[gpx];

  float acc[8];
#pragma unroll
  for (int i = 0; i < 8; ++i) acc[i] = 0.f;

  const int lo = (h - 3 < 0) ? 0 : h - 3;
  const int hi = (h + 3 > 63) ? 63 : h + 3;
  float l = 7.0f * (float)(6 - (hi - lo));   // skipped rows: 7 x exp(0)

  LOAD(lo);
  WRITE(0);
  __syncthreads();

  int buf = 0;
  for (int ar = lo; ar <= hi; ++ar) {
    if (ar < hi) LOAD(ar + 1);               // issue early: hides under compute
#pragma unroll
    for (int dx = -3; dx <= 3; ++dx) {
      const int j = w + 4 + dx;
      const float4 nv0 = *(const float4*)&fs[buf][j][cb];
      const float4 nv1 = *(const float4*)&fs[buf][j][cb + 4];
      float d = fmaf(fc[0], nv0.x,
                fmaf(fc[1], nv0.y,
                fmaf(fc[2], nv0.z,
                fmaf(fc[3], nv0.w,
                fmaf(fc[4], nv1.x,
                fmaf(fc[5], nv1.y,
                fmaf(fc[6], nv1.z, fc[7] * nv1.w)))))));
      d = dpp8_sum(d);                 // 8-lane reduce, VALU-only
      const float cnk = cnS[buf][j];
      float sim = d * __builtin_amdgcn_rcpf(fmaxf(cnc * cnk, 1e-8f));
      const bool valid = (unsigned)(w + dx) < 64u;
      sim = valid ? sim : 0.f;         // select: NaN/Inf-safe
      const float p = __expf(sim);     // sim <= 1 -> p <= e
      l += p;
      const float pv = valid ? p : 0.f;
      acc[0] = fmaf(pv, nv0.x, acc[0]);
      acc[1] = fmaf(pv, nv0.y, acc[1]);
      acc[2] = fmaf(pv, nv0.z, acc[2]);
      acc[3] = fmaf(pv, nv0.w, acc[3]);
      acc[4] = fmaf(pv, nv1.x, acc[4]);
      acc[5] = fmaf(pv, nv1.y, acc[5]);
      acc[6] = fmaf(pv, nv1.z, acc[6]);
      acc[7] = fmaf(pv, nv1.w, acc[7]);
    }
    if (ar < hi) WRITE(buf ^ 1);             // vmcnt waits here, not earlier
    __syncthreads();
    buf ^= 1;
  }

  // normalized corr -> f16 corrH[px w][k cb..cb+7], XOR-swizzled, b128 write
  {
    const float inv = __builtin_amdgcn_rcpf(l);
    half8 hv;
#pragma unroll
    for (int i = 0; i < 8; ++i) hv[i] = (_Float16)(acc[i] * inv);
    const int wbyte = (w * 128 + (cb << 1)) ^ ((w & 7) << 4);
    *(half8*)((char*)corrH + wbyte) = hv;
  }
  __syncthreads();

  // ---- Phase B: MFMA proj. Wave g -> outs [g*64, g*64+64) x 64 px.
  const _Float16* wA = wpH + (size_t)g * 4096;
  float* outb = out + ((size_t)b * COUT + g * 64) * NPIX + h * 64;
#pragma unroll
  for (int pt = 0; pt < 4; ++pt) {
    half8 Bf0, Bf1;
    {
      const int pxl = pt * 16 + (lane & 15);
      const int sw = (pxl & 7) << 4;
      const int rowb = pxl * 128 + ((lane >> 4) << 4);
      Bf0 = *(const half8*)((const char*)corrH + (rowb ^ sw));
      Bf1 = *(const half8*)((const char*)corrH + ((rowb + 64) ^ sw));
    }
#pragma unroll
    for (int ot = 0; ot < 4; ++ot) {
      f32x4 c = {0.f, 0.f, 0.f, 0.f};
      const half8 A0 = *(const half8*)(wA + (ot * 2 + 0) * 512 + lane * 8);
      const half8 A1 = *(const half8*)(wA + (ot * 2 + 1) * 512 + lane * 8);
      c = __builtin_amdgcn_mfma_f32_16x16x32_f16(A0, Bf0, c, 0, 0, 0);
      c = __builtin_amdgcn_mfma_f32_16x16x32_f16(A1, Bf1, c, 0, 0, 0);
      float* op = outb + (size_t)(ot * 16 + ((lane >> 4) << 2)) * NPIX
                       + pt * 16 + (lane & 15);
#pragma unroll
      for (int r = 0; r < 4; ++r) op[(size_t)r * NPIX] = c[r];
    }
  }
}

// ---------------------------------------------------------------------------
extern "C" void kernel_launch(void* const* d_in, const int* in_sizes, int n_in,
                              void* d_out, int out_size, void* d_ws, size_t ws_size,
                              hipStream_t stream)
{
  const float* x  = (const float*)d_in[0];
  const float* wr = (const float*)d_in[1];
  const float* wp = (const float*)d_in[2];
  float* out = (float*)d_out;

  // ws layout (floats):
  //   wrT[16384] | wpH[32768 f16 = 16384 floats] | [CG] cnorm[8*4096] [CG] |
  //   feat[8*64*4096] (c-major) | [FT tail guard]
  float* ws = (float*)d_ws;
  float* wrT      = ws;
  _Float16* wpH   = (_Float16*)(ws + CR * CIN);
  float* cnormG   = ws + CR * CIN + (COUT * CR) / 2;   // guarded region base
  float* cnorm    = cnormG + CG;
  float* feat     = cnorm + NB * NPIX + CG;
  float* featTail = feat + (size_t)NB * CR * NPIX;

  hipLaunchKernelGGL(k0_prep,   dim3(195), dim3(256), 0, stream, wr, wp, wrT, wpH, cnormG, featTail);
  hipLaunchKernelGGL(k1_reduce, dim3(512), dim3(512), 0, stream, x, wrT, feat, cnorm);
  hipLaunchKernelGGL(k23_fused, dim3(512), dim3(512), 0, stream, feat, cnorm, wpH, out);
}

// Round 13
// 46.189 us; speedup vs baseline: 4.5332x; 1.2219x over previous
//
#include <hip/hip_runtime.h>
#include <stdint.h>

#define NPIX 4096
#define CIN  256
#define CR   64
#define COUT 512
#define NB   8
#define CG   256     // cnorm guard floats each side
#define FT   128     // feat tail guard

typedef _Float16 half8 __attribute__((ext_vector_type(8)));
typedef float f32x4 __attribute__((ext_vector_type(4)));

// 8-lane sum (groups aligned to 8): quad_perm xor1, xor2, then row_half_mirror
// pulls the other quad's total. Pure VALU - no DS pipe.
__device__ __forceinline__ float dpp8_sum(float d) {
  int y;
  y = __builtin_amdgcn_update_dpp(0, __float_as_int(d), 0xB1, 0xF, 0xF, true);
  d += __int_as_float(y);
  y = __builtin_amdgcn_update_dpp(0, __float_as_int(d), 0x4E, 0xF, 0xF, true);
  d += __int_as_float(y);
  y = __builtin_amdgcn_update_dpp(0, __float_as_int(d), 0x141, 0xF, 0xF, true);
  d += __int_as_float(y);
  return d;
}

// ---------------------------------------------------------------------------
// K0: pack w_reduce into hi/lo fp16 A-fragments (for k1's MFMA), wp into fp16
// A-fragments (for k23 phase B), zero guard zones.
// A-frag layout (16x16x32, HW-verified r11): lane l holds 8 elems
// A[m = l&15][k = kt*32 + (l>>4)*8 + j], stored at frag*512 + l*8 + j.
// wr frags: frag = mt*8 + kt (mt 0..3, kt 0..7). hi/lo: v = hi + lo + O(2^-22).
// ---------------------------------------------------------------------------
__global__ __launch_bounds__(256) void k0_prep(
    const float* __restrict__ wr, const float* __restrict__ wp,
    _Float16* __restrict__ wrAh, _Float16* __restrict__ wrAl,
    _Float16* __restrict__ wpH,
    float* __restrict__ cnormG, float* __restrict__ featTail)
{
  const int tid = blockIdx.x * 256 + threadIdx.x;
  if (tid < 16384) {                          // wr[64][256] -> hi/lo A-frags
    const int j = tid & 7, l = (tid >> 3) & 63;
    const int kt = (tid >> 9) & 7, mt = tid >> 12;
    const int m = mt * 16 + (l & 15);
    const int k = kt * 32 + (l >> 4) * 8 + j;
    const float v = wr[m * CIN + k];
    const _Float16 h = (_Float16)v;
    wrAh[tid] = h;
    wrAl[tid] = (_Float16)(v - (float)h);
  } else if (tid < 16384 + COUT * CR) {       // wp[512][64] -> A-frags f16
    const int fi = tid - 16384;
    const int j = fi & 7, l = (fi >> 3) & 63;
    const int kt = (fi >> 9) & 1, ot = (fi >> 10) & 3, g = fi >> 12;
    const int o = g * 64 + ot * 16 + (l & 15);
    const int k = kt * 32 + (l >> 4) * 8 + j;
    wpH[fi] = (_Float16)wp[o * CR + k];
  } else {
    const int gi = tid - (16384 + COUT * CR);
    if (gi < CG)               cnormG[gi] = 0.f;                         // head
    else if (gi < 2 * CG)      cnormG[CG + NB * NPIX + (gi - CG)] = 0.f; // tail
    else if (gi < 2 * CG + FT) featTail[gi - 2 * CG] = 0.f;              // feat tail
  }
}

// ---------------------------------------------------------------------------
// K1 (MFMA): feat[b,c,px] = sum_k wr[c][k] * x[b,k,px]; cnorm = sqrt(sum feat^2).
// GEMM M=64(ch) x N=64(px tile) x K=256 per block; 512 blocks x 8 waves.
// Wave g: nt = g&3 (px sub-tile), mth = g>>2 (row half); 2 C-tiles/wave.
// B (x) converted to hi/lo fp16 on the fly; A pre-packed by k0.
// C = Ah*Bh + Ah*Bl + Al*Bh  (fp32-class accuracy, err ~2^-22).
// cnorm: per-lane column sums of C^2, shfl_xor(16,32), LDS combine.
// ---------------------------------------------------------------------------
__global__ __launch_bounds__(512) void k1_reduce(
    const float* __restrict__ x,
    const _Float16* __restrict__ wrAh, const _Float16* __restrict__ wrAl,
    float* __restrict__ feat, float* __restrict__ cnorm)
{
  const int blk = blockIdx.x;             // 512 = b(3b) | seg(6b)
  const int b = blk >> 6, seg = blk & 63;
  const int t = threadIdx.x, lane = t & 63;
  const int g = __builtin_amdgcn_readfirstlane((int)t >> 6);  // 0..7
  const int nt = g & 3, mth = g >> 2;
  const int col = lane & 15, krow = lane >> 4;

  const float* xb = x + (size_t)b * CIN * NPIX + seg * 64 + nt * 16 + col;

  f32x4 c0 = {0.f, 0.f, 0.f, 0.f};
  f32x4 c1 = {0.f, 0.f, 0.f, 0.f};

#pragma unroll
  for (int kt = 0; kt < 8; ++kt) {
    // B-frag: k = kt*32 + krow*8 + j, n = col
    half8 Bh, Bl;
    const float* xk = xb + (size_t)(kt * 32 + krow * 8) * NPIX;
#pragma unroll
    for (int j = 0; j < 8; ++j) {
      const float v = xk[(size_t)j * NPIX];
      const _Float16 h = (_Float16)v;
      Bh[j] = h;
      Bl[j] = (_Float16)(v - (float)h);
    }
    const int fi0 = ((mth * 2 + 0) * 8 + kt) * 512 + lane * 8;
    const int fi1 = ((mth * 2 + 1) * 8 + kt) * 512 + lane * 8;
    const half8 Ah0 = *(const half8*)(wrAh + fi0);
    const half8 Al0 = *(const half8*)(wrAl + fi0);
    const half8 Ah1 = *(const half8*)(wrAh + fi1);
    const half8 Al1 = *(const half8*)(wrAl + fi1);
    c0 = __builtin_amdgcn_mfma_f32_16x16x32_f16(Ah0, Bh, c0, 0, 0, 0);
    c0 = __builtin_amdgcn_mfma_f32_16x16x32_f16(Ah0, Bl, c0, 0, 0, 0);
    c0 = __builtin_amdgcn_mfma_f32_16x16x32_f16(Al0, Bh, c0, 0, 0, 0);
    c1 = __builtin_amdgcn_mfma_f32_16x16x32_f16(Ah1, Bh, c1, 0, 0, 0);
    c1 = __builtin_amdgcn_mfma_f32_16x16x32_f16(Ah1, Bl, c1, 0, 0, 0);
    c1 = __builtin_amdgcn_mfma_f32_16x16x32_f16(Al1, Bh, c1, 0, 0, 0);
  }

  // C layout (HW-verified): col = lane&15, row = krow*4 + r
  float p = 0.f;
  float* fbase = feat + (size_t)b * CR * NPIX + seg * 64 + nt * 16 + col;
#pragma unroll
  for (int r = 0; r < 4; ++r) {
    const int m0 = (mth * 2 + 0) * 16 + krow * 4 + r;
    const int m1 = (mth * 2 + 1) * 16 + krow * 4 + r;
    fbase[(size_t)m0 * NPIX] = c0[r];
    fbase[(size_t)m1 * NPIX] = c1[r];
    p = fmaf(c0[r], c0[r], p);
    p = fmaf(c1[r], c1[r], p);
  }
  // sum over krow groups (same col): lanes l, l^16, l^32, l^48
  p += __shfl_xor(p, 16);
  p += __shfl_xor(p, 32);

  __shared__ float cn[8][16];
  if (lane < 16) cn[g][lane] = p;
  __syncthreads();
  if (t < 64) {
    const int nt2 = t >> 4, c16 = t & 15;
    cnorm[b * NPIX + seg * 64 + t] = sqrtf(cn[nt2][c16] + cn[nt2 + 4][c16]);
  }
}

// ---------------------------------------------------------------------------
// K23: fused correlation-softmax-attention (fp32) + projection (fp16 MFMA).
// (unchanged from round 11 - see comments there)
// ---------------------------------------------------------------------------
__global__ __launch_bounds__(512, 4) void k23_fused(
    const float* __restrict__ feat, const float* __restrict__ cnorm,
    const _Float16* __restrict__ wpH, float* __restrict__ out)
{
  const int blk = blockIdx.x;          // 512
  const int b = blk & 7, h = blk >> 3; // XCD-aware: xcd = blk % 8 = b
  const int t = threadIdx.x;
  const int lane = t & 63;
  const int g = __builtin_amdgcn_readfirstlane((int)t >> 6);  // 0..7
  const int w = t >> 3;                // px col 0..63
  const int cb = (t & 7) * 8;          // channel base for this lane
  const int px = h * 64 + w;
  const int gpx = b * NPIX + px;

  const float* fb = feat + (size_t)b * CR * NPIX;
  const float* cnb = cnorm + b * NPIX;

  __shared__ float fs[2][72][68];                  // 39168 B: [px j][ch]
  __shared__ float cnS[2][80];                     // 640 B
  __shared__ __align__(16) _Float16 corrH[4096];   // 8192 B: [px][k] swizzled

  float rA[2][4];
  float rB[4];
  float rc = 0.f;
  const int jt = 64 + (t >> 4), c4t = t & 15;

  auto LOAD = [&](int ar) {
    const int base = ar * 64 - 4;      // overhang covered by guards
#pragma unroll
    for (int k = 0; k < 2; ++k) {
      const int c4 = g * 2 + k;
#pragma unroll
      for (int q = 0; q < 4; ++q)
        rA[k][q] = fb[(size_t)(c4 * 4 + q) * NPIX + base + lane];  // coalesced
    }
    if (t < 128) {
#pragma unroll
      for (int q = 0; q < 4; ++q)
        rB[q] = fb[(size_t)(c4t * 4 + q) * NPIX + base + jt];
    }
    if (t < 72) rc = cnb[base + t];
  };
  auto WRITE = [&](int bufi) {
#pragma unroll
    for (int k = 0; k < 2; ++k) {
      const int c4 = g * 2 + k;
      *(float4*)&fs[bufi][lane][c4 * 4] =
          make_float4(rA[k][0], rA[k][1], rA[k][2], rA[k][3]);
    }
    if (t < 128)
      *(float4*)&fs[bufi][jt][c4t * 4] = make_float4(rB[0], rB[1], rB[2], rB[3]);
    if (t < 72) cnS[bufi][t] = rc;
  };

  const float* fpx = fb + (size_t)cb * NPIX + px;
  float fc[8];
#pragma unroll
  for (int i = 0; i < 8; ++i) fc[i] = fpx[i * NPIX];
  const float cnc = cnorm[gpx];

  float acc[8];
#pragma unroll
  for (int i = 0; i < 8; ++i) acc[i] = 0.f;

  const int lo = (h - 3 < 0) ? 0 : h - 3;
  const int hi = (h + 3 > 63) ? 63 : h + 3;
  float l = 7.0f * (float)(6 - (hi - lo));   // skipped rows: 7 x exp(0)

  LOAD(lo);
  WRITE(0);
  __syncthreads();

  int buf = 0;
  for (int ar = lo; ar <= hi; ++ar) {
    if (ar < hi) LOAD(ar + 1);               // issue early: hides under compute
#pragma unroll
    for (int dx = -3; dx <= 3; ++dx) {
      const int j = w + 4 + dx;
      const float4 nv0 = *(const float4*)&fs[buf][j][cb];
      const float4 nv1 = *(const float4*)&fs[buf][j][cb + 4];
      float d = fmaf(fc[0], nv0.x,
                fmaf(fc[1], nv0.y,
                fmaf(fc[2], nv0.z,
                fmaf(fc[3], nv0.w,
                fmaf(fc[4], nv1.x,
                fmaf(fc[5], nv1.y,
                fmaf(fc[6], nv1.z, fc[7] * nv1.w)))))));
      d = dpp8_sum(d);                 // 8-lane reduce, VALU-only
      const float cnk = cnS[buf][j];
      float sim = d * __builtin_amdgcn_rcpf(fmaxf(cnc * cnk, 1e-8f));
      const bool valid = (unsigned)(w + dx) < 64u;
      sim = valid ? sim : 0.f;         // select: NaN/Inf-safe
      const float p = __expf(sim);     // sim <= 1 -> p <= e
      l += p;
      const float pv = valid ? p : 0.f;
      acc[0] = fmaf(pv, nv0.x, acc[0]);
      acc[1] = fmaf(pv, nv0.y, acc[1]);
      acc[2] = fmaf(pv, nv0.z, acc[2]);
      acc[3] = fmaf(pv, nv0.w, acc[3]);
      acc[4] = fmaf(pv, nv1.x, acc[4]);
      acc[5] = fmaf(pv, nv1.y, acc[5]);
      acc[6] = fmaf(pv, nv1.z, acc[6]);
      acc[7] = fmaf(pv, nv1.w, acc[7]);
    }
    if (ar < hi) WRITE(buf ^ 1);             // vmcnt waits here, not earlier
    __syncthreads();
    buf ^= 1;
  }

  // normalized corr -> f16 corrH[px w][k cb..cb+7], XOR-swizzled, b128 write
  {
    const float inv = __builtin_amdgcn_rcpf(l);
    half8 hv;
#pragma unroll
    for (int i = 0; i < 8; ++i) hv[i] = (_Float16)(acc[i] * inv);
    const int wbyte = (w * 128 + (cb << 1)) ^ ((w & 7) << 4);
    *(half8*)((char*)corrH + wbyte) = hv;
  }
  __syncthreads();

  // ---- Phase B: MFMA proj. Wave g -> outs [g*64, g*64+64) x 64 px.
  const _Float16* wA = wpH + (size_t)g * 4096;
  float* outb = out + ((size_t)b * COUT + g * 64) * NPIX + h * 64;
#pragma unroll
  for (int pt = 0; pt < 4; ++pt) {
    half8 Bf0, Bf1;
    {
      const int pxl = pt * 16 + (lane & 15);
      const int sw = (pxl & 7) << 4;
      const int rowb = pxl * 128 + ((lane >> 4) << 4);
      Bf0 = *(const half8*)((const char*)corrH + (rowb ^ sw));
      Bf1 = *(const half8*)((const char*)corrH + ((rowb + 64) ^ sw));
    }
#pragma unroll
    for (int ot = 0; ot < 4; ++ot) {
      f32x4 c = {0.f, 0.f, 0.f, 0.f};
      const half8 A0 = *(const half8*)(wA + (ot * 2 + 0) * 512 + lane * 8);
      const half8 A1 = *(const half8*)(wA + (ot * 2 + 1) * 512 + lane * 8);
      c = __builtin_amdgcn_mfma_f32_16x16x32_f16(A0, Bf0, c, 0, 0, 0);
      c = __builtin_amdgcn_mfma_f32_16x16x32_f16(A1, Bf1, c, 0, 0, 0);
      float* op = outb + (size_t)(ot * 16 + ((lane >> 4) << 2)) * NPIX
                       + pt * 16 + (lane & 15);
#pragma unroll
      for (int r = 0; r < 4; ++r) op[(size_t)r * NPIX] = c[r];
    }
  }
}

// ---------------------------------------------------------------------------
extern "C" void kernel_launch(void* const* d_in, const int* in_sizes, int n_in,
                              void* d_out, int out_size, void* d_ws, size_t ws_size,
                              hipStream_t stream)
{
  const float* x  = (const float*)d_in[0];
  const float* wr = (const float*)d_in[1];
  const float* wp = (const float*)d_in[2];
  float* out = (float*)d_out;

  // ws layout (float-slots):
  //   wrAh[16384 h = 8192] | wrAl[16384 h = 8192] | wpH[32768 h = 16384] |
  //   [CG] cnorm[8*4096] [CG] | feat[8*64*4096] (c-major) | [FT tail guard]
  float* ws = (float*)d_ws;
  _Float16* wrAh  = (_Float16*)ws;
  _Float16* wrAl  = (_Float16*)(ws + 8192);
  _Float16* wpH   = (_Float16*)(ws + 16384);
  float* cnormG   = ws + 32768;             // guarded region base
  float* cnorm    = cnormG + CG;
  float* feat     = cnorm + NB * NPIX + CG;
  float* featTail = feat + (size_t)NB * CR * NPIX;

  hipLaunchKernelGGL(k0_prep,   dim3(195), dim3(256), 0, stream, wr, wp, wrAh, wrAl, wpH, cnormG, featTail);
  hipLaunchKernelGGL(k1_reduce, dim3(512), dim3(512), 0, stream, x, wrAh, wrAl, feat, cnorm);
  hipLaunchKernelGGL(k23_fused, dim3(512), dim3(512), 0, stream, feat, cnorm, wpH, out);
}

// Round 14
// 41.102 us; speedup vs baseline: 5.0942x; 1.1238x over previous
//
#include <hip/hip_runtime.h>
#include <stdint.h>

#define NPIX 4096
#define CIN  256
#define CR   64
#define COUT 512
#define NB   8
#define CG   256     // cnorm guard floats each side (also covers feat_h head)
#define FT   128     // feat_h tail guard (floats; covers +4 px overhang)

typedef _Float16 half8 __attribute__((ext_vector_type(8)));
typedef _Float16 half4 __attribute__((ext_vector_type(4)));
typedef _Float16 half2v __attribute__((ext_vector_type(2)));
typedef float f32x4 __attribute__((ext_vector_type(4)));

// 8-lane sum (groups aligned to 8): quad_perm xor1, xor2, then row_half_mirror.
__device__ __forceinline__ float dpp8_sum(float d) {
  int y;
  y = __builtin_amdgcn_update_dpp(0, __float_as_int(d), 0xB1, 0xF, 0xF, true);
  d += __int_as_float(y);
  y = __builtin_amdgcn_update_dpp(0, __float_as_int(d), 0x4E, 0xF, 0xF, true);
  d += __int_as_float(y);
  y = __builtin_amdgcn_update_dpp(0, __float_as_int(d), 0x141, 0xF, 0xF, true);
  d += __int_as_float(y);
  return d;
}

// ---------------------------------------------------------------------------
// K0: pack w_reduce into hi/lo fp16 A-fragments (k1 MFMA), wp into fp16
// A-fragments (k23 phase B), zero guard zones. (unchanged from r12)
// ---------------------------------------------------------------------------
__global__ __launch_bounds__(256) void k0_prep(
    const float* __restrict__ wr, const float* __restrict__ wp,
    _Float16* __restrict__ wrAh, _Float16* __restrict__ wrAl,
    _Float16* __restrict__ wpH,
    float* __restrict__ cnormG, float* __restrict__ featTail)
{
  const int tid = blockIdx.x * 256 + threadIdx.x;
  if (tid < 16384) {                          // wr[64][256] -> hi/lo A-frags
    const int j = tid & 7, l = (tid >> 3) & 63;
    const int kt = (tid >> 9) & 7, mt = tid >> 12;
    const int m = mt * 16 + (l & 15);
    const int k = kt * 32 + (l >> 4) * 8 + j;
    const float v = wr[m * CIN + k];
    const _Float16 h = (_Float16)v;
    wrAh[tid] = h;
    wrAl[tid] = (_Float16)(v - (float)h);
  } else if (tid < 16384 + COUT * CR) {       // wp[512][64] -> A-frags f16
    const int fi = tid - 16384;
    const int j = fi & 7, l = (fi >> 3) & 63;
    const int kt = (fi >> 9) & 1, ot = (fi >> 10) & 3, g = fi >> 12;
    const int o = g * 64 + ot * 16 + (l & 15);
    const int k = kt * 32 + (l >> 4) * 8 + j;
    wpH[fi] = (_Float16)wp[o * CR + k];
  } else {
    const int gi = tid - (16384 + COUT * CR);
    if (gi < CG)               cnormG[gi] = 0.f;                         // head
    else if (gi < 2 * CG)      cnormG[CG + NB * NPIX + (gi - CG)] = 0.f; // tail
    else if (gi < 2 * CG + FT) featTail[gi - 2 * CG] = 0.f;              // feat tail
  }
}

// ---------------------------------------------------------------------------
// K1 (MFMA): feat_h[b,px,ch] (f16, px-major) = sum_k wr[c][k]*x[b,k,px];
// cnorm (f32) = sqrt(sum_c feat^2).  C = Ah*Bh + Ah*Bl + Al*Bh (fp32-class).
// 512 blocks x 8 waves; wave g: nt=g&3 px sub-tile, mth=g>>2 row half.
// ---------------------------------------------------------------------------
__global__ __launch_bounds__(512) void k1_reduce(
    const float* __restrict__ x,
    const _Float16* __restrict__ wrAh, const _Float16* __restrict__ wrAl,
    _Float16* __restrict__ feat_h, float* __restrict__ cnorm)
{
  const int blk = blockIdx.x;             // 512 = b(3b) | seg(6b)
  const int b = blk >> 6, seg = blk & 63;
  const int t = threadIdx.x, lane = t & 63;
  const int g = __builtin_amdgcn_readfirstlane((int)t >> 6);  // 0..7
  const int nt = g & 3, mth = g >> 2;
  const int col = lane & 15, krow = lane >> 4;

  const float* xb = x + (size_t)b * CIN * NPIX + seg * 64 + nt * 16 + col;

  f32x4 c0 = {0.f, 0.f, 0.f, 0.f};
  f32x4 c1 = {0.f, 0.f, 0.f, 0.f};

#pragma unroll
  for (int kt = 0; kt < 8; ++kt) {
    half8 Bh, Bl;
    const float* xk = xb + (size_t)(kt * 32 + krow * 8) * NPIX;
#pragma unroll
    for (int j = 0; j < 8; ++j) {
      const float v = xk[(size_t)j * NPIX];
      const _Float16 h = (_Float16)v;
      Bh[j] = h;
      Bl[j] = (_Float16)(v - (float)h);
    }
    const int fi0 = ((mth * 2 + 0) * 8 + kt) * 512 + lane * 8;
    const int fi1 = ((mth * 2 + 1) * 8 + kt) * 512 + lane * 8;
    const half8 Ah0 = *(const half8*)(wrAh + fi0);
    const half8 Al0 = *(const half8*)(wrAl + fi0);
    const half8 Ah1 = *(const half8*)(wrAh + fi1);
    const half8 Al1 = *(const half8*)(wrAl + fi1);
    c0 = __builtin_amdgcn_mfma_f32_16x16x32_f16(Ah0, Bh, c0, 0, 0, 0);
    c0 = __builtin_amdgcn_mfma_f32_16x16x32_f16(Ah0, Bl, c0, 0, 0, 0);
    c0 = __builtin_amdgcn_mfma_f32_16x16x32_f16(Al0, Bh, c0, 0, 0, 0);
    c1 = __builtin_amdgcn_mfma_f32_16x16x32_f16(Ah1, Bh, c1, 0, 0, 0);
    c1 = __builtin_amdgcn_mfma_f32_16x16x32_f16(Ah1, Bl, c1, 0, 0, 0);
    c1 = __builtin_amdgcn_mfma_f32_16x16x32_f16(Al1, Bh, c1, 0, 0, 0);
  }

  // C layout (HW-verified): col = lane&15, row = krow*4 + r (consecutive ch)
  const int px = seg * 64 + nt * 16 + col;
  _Float16* fb = feat_h + ((size_t)b * NPIX + px) * 64;
  const int ch0 = mth * 32 + krow * 4;
  half4 v0, v1;
  float p = 0.f;
#pragma unroll
  for (int r = 0; r < 4; ++r) {
    v0[r] = (_Float16)c0[r];
    v1[r] = (_Float16)c1[r];
    p = fmaf(c0[r], c0[r], p);
    p = fmaf(c1[r], c1[r], p);
  }
  *(half4*)(fb + ch0) = v0;
  *(half4*)(fb + ch0 + 16) = v1;

  p += __shfl_xor(p, 16);
  p += __shfl_xor(p, 32);

  __shared__ float cn[8][16];
  if (lane < 16) cn[g][lane] = p;
  __syncthreads();
  if (t < 64) {
    const int nt2 = t >> 4, c16 = t & 15;
    cnorm[b * NPIX + seg * 64 + t] = sqrtf(cn[nt2][c16] + cn[nt2 + 4][c16]);
  }
}

// ---------------------------------------------------------------------------
// K23: fused correlation-softmax-attention (f16 packed) + projection (MFMA).
// Block = (b,h) row of 64 px, 512 thr (8 waves). XCD map b=blk&7.
//
// Staging: feat_h is px-major -> row tile (72px x 64ch f16 = 9216 B) is one
// CONTIGUOUS byte range; thread t copies h8 at rowb+t*8 (t<512) and
// rowb+(512+t)*8 (t<64) -> fully coalesced loads + bank-balanced b128 writes.
// T14 split: LOAD before compute, WRITE after. fs rows padded to 72 f16.
//
// Phase A per neighbor: 1x ds_read_b128 (8ch f16), dot = 4x v_dot2_f32_f16
// (f32 acc), 8-lane combine via DPP, one-pass softmax (sim<=1 -> exp<=e),
// attended accum = 4x v_pk_fma_f16 into 2 alternating h2 accumulators
// (combined in f32 at end). OOB rows skipped (l+=7); OOB cols select-masked;
// all staged overhang bytes finite (guards zeroed / feat interior).
//
// Phase B: corr -> f16 corrH[px][64k] XOR-swizzled; wave g -> outs
// [g*64,g*64+64) via 2x mfma_f32_16x16x32_f16 per 16x16 tile. (r11-verified)
// ---------------------------------------------------------------------------
__global__ __launch_bounds__(512, 4) void k23_fused(
    const _Float16* __restrict__ feat_h, const float* __restrict__ cnorm,
    const _Float16* __restrict__ wpH, float* __restrict__ out)
{
  const int blk = blockIdx.x;          // 512
  const int b = blk & 7, h = blk >> 3; // XCD-aware: xcd = blk % 8 = b
  const int t = threadIdx.x;
  const int lane = t & 63;
  const int g = __builtin_amdgcn_readfirstlane((int)t >> 6);  // 0..7
  const int w = t >> 3;                // px col 0..63
  const int cb = (t & 7) * 8;          // channel base for this lane
  const int px = h * 64 + w;
  const int gpx = b * NPIX + px;

  const float* cnb = cnorm + b * NPIX;

  __shared__ __align__(16) _Float16 fs[2][72][72];   // 20736 B, 144 B rows
  __shared__ float cnS[2][80];                       // 640 B
  __shared__ __align__(16) _Float16 corrH[4096];     // 8192 B

  half8 rS0, rS1;
  float rc = 0.f;

  auto LOAD = [&](int ar) {
    const long rowb = ((long)b * NPIX + ar * 64 - 4) * 64;  // f16 units
    rS0 = *(const half8*)(feat_h + rowb + (long)t * 8);     // contiguous
    if (t < 64) rS1 = *(const half8*)(feat_h + rowb + (long)(512 + t) * 8);
    if (t < 72) rc = cnb[ar * 64 - 4 + t];
  };
  auto WRITE = [&](int bufi) {
    *(half8*)&fs[bufi][t >> 3][(t & 7) * 8] = rS0;
    if (t < 64) *(half8*)&fs[bufi][64 + (t >> 3)][(t & 7) * 8] = rS1;
    if (t < 72) cnS[bufi][t] = rc;
  };

  // center features (f16, contiguous 16 B per lane)
  half2v fc2[4];
  {
    const half8 fcv = *(const half8*)(feat_h + ((size_t)b * NPIX + px) * 64 + cb);
#pragma unroll
    for (int i = 0; i < 4; ++i) { fc2[i][0] = fcv[2*i]; fc2[i][1] = fcv[2*i+1]; }
  }
  const float cnc = cnorm[gpx];

  half2v accA[4], accB[4];
#pragma unroll
  for (int i = 0; i < 4; ++i) {
    accA[i] = (half2v)(_Float16)0.f;
    accB[i] = (half2v)(_Float16)0.f;
  }

  const int lo = (h - 3 < 0) ? 0 : h - 3;
  const int hi = (h + 3 > 63) ? 63 : h + 3;
  float l = 7.0f * (float)(6 - (hi - lo));   // skipped rows: 7 x exp(0)

  LOAD(lo);
  WRITE(0);
  __syncthreads();

  int buf = 0;
  for (int ar = lo; ar <= hi; ++ar) {
    if (ar < hi) LOAD(ar + 1);               // issue early: hides under compute
#pragma unroll
    for (int dx = -3; dx <= 3; ++dx) {
      const int j = w + 4 + dx;
      const half8 nv = *(const half8*)&fs[buf][j][cb];
      half2v n0, n1, n2, n3;
      n0[0] = nv[0]; n0[1] = nv[1];
      n1[0] = nv[2]; n1[1] = nv[3];
      n2[0] = nv[4]; n2[1] = nv[5];
      n3[0] = nv[6]; n3[1] = nv[7];
      float d = 0.f;
      d = __builtin_amdgcn_fdot2(fc2[0], n0, d, false);
      d = __builtin_amdgcn_fdot2(fc2[1], n1, d, false);
      d = __builtin_amdgcn_fdot2(fc2[2], n2, d, false);
      d = __builtin_amdgcn_fdot2(fc2[3], n3, d, false);
      d = dpp8_sum(d);                 // 8-lane reduce, VALU-only
      const float cnk = cnS[buf][j];
      float sim = d * __builtin_amdgcn_rcpf(fmaxf(cnc * cnk, 1e-8f));
      const bool valid = (unsigned)(w + dx) < 64u;
      sim = valid ? sim : 0.f;         // select: NaN/Inf-safe
      const float p = __expf(sim);     // sim <= 1 -> p <= e
      l += p;
      const float pv = valid ? p : 0.f;
      const _Float16 ph = (_Float16)pv;
      half2v ph2; ph2[0] = ph; ph2[1] = ph;
      if (dx & 1) {
        accA[0] = ph2 * n0 + accA[0];
        accA[1] = ph2 * n1 + accA[1];
        accA[2] = ph2 * n2 + accA[2];
        accA[3] = ph2 * n3 + accA[3];
      } else {
        accB[0] = ph2 * n0 + accB[0];
        accB[1] = ph2 * n1 + accB[1];
        accB[2] = ph2 * n2 + accB[2];
        accB[3] = ph2 * n3 + accB[3];
      }
    }
    if (ar < hi) WRITE(buf ^ 1);             // vmcnt waits here, not earlier
    __syncthreads();
    buf ^= 1;
  }

  // combine f16 partials in f32, normalize, write f16 corrH (XOR-swizzled)
  {
    const float inv = __builtin_amdgcn_rcpf(l);
    half8 hv;
#pragma unroll
    for (int i = 0; i < 4; ++i) {
      const float a0 = (float)accA[i][0] + (float)accB[i][0];
      const float a1 = (float)accA[i][1] + (float)accB[i][1];
      hv[2*i]   = (_Float16)(a0 * inv);
      hv[2*i+1] = (_Float16)(a1 * inv);
    }
    const int wbyte = (w * 128 + (cb << 1)) ^ ((w & 7) << 4);
    *(half8*)((char*)corrH + wbyte) = hv;
  }
  __syncthreads();

  // ---- Phase B: MFMA proj. Wave g -> outs [g*64, g*64+64) x 64 px.
  const _Float16* wA = wpH + (size_t)g * 4096;
  float* outb = out + ((size_t)b * COUT + g * 64) * NPIX + h * 64;
#pragma unroll
  for (int pt = 0; pt < 4; ++pt) {
    half8 Bf0, Bf1;
    {
      const int pxl = pt * 16 + (lane & 15);
      const int sw = (pxl & 7) << 4;
      const int rowb = pxl * 128 + ((lane >> 4) << 4);
      Bf0 = *(const half8*)((const char*)corrH + (rowb ^ sw));
      Bf1 = *(const half8*)((const char*)corrH + ((rowb + 64) ^ sw));
    }
#pragma unroll
    for (int ot = 0; ot < 4; ++ot) {
      f32x4 c = {0.f, 0.f, 0.f, 0.f};
      const half8 A0 = *(const half8*)(wA + (ot * 2 + 0) * 512 + lane * 8);
      const half8 A1 = *(const half8*)(wA + (ot * 2 + 1) * 512 + lane * 8);
      c = __builtin_amdgcn_mfma_f32_16x16x32_f16(A0, Bf0, c, 0, 0, 0);
      c = __builtin_amdgcn_mfma_f32_16x16x32_f16(A1, Bf1, c, 0, 0, 0);
      float* op = outb + (size_t)(ot * 16 + ((lane >> 4) << 2)) * NPIX
                       + pt * 16 + (lane & 15);
#pragma unroll
      for (int r = 0; r < 4; ++r) op[(size_t)r * NPIX] = c[r];
    }
  }
}

// ---------------------------------------------------------------------------
extern "C" void kernel_launch(void* const* d_in, const int* in_sizes, int n_in,
                              void* d_out, int out_size, void* d_ws, size_t ws_size,
                              hipStream_t stream)
{
  const float* x  = (const float*)d_in[0];
  const float* wr = (const float*)d_in[1];
  const float* wp = (const float*)d_in[2];
  float* out = (float*)d_out;

  // ws layout (float-slots):
  //   wrAh[8192] | wrAl[8192] | wpH[16384] |
  //   [CG] cnorm[8*4096] [CG] | feat_h[8*4096*64 f16 = 1M floats] | [FT]
  // feat_h head overhang (-4 px = 512 B) covered by cnorm tail guard (1 KB);
  // tail overhang (+4 px) covered by FT guard.
  float* ws = (float*)d_ws;
  _Float16* wrAh  = (_Float16*)ws;
  _Float16* wrAl  = (_Float16*)(ws + 8192);
  _Float16* wpH   = (_Float16*)(ws + 16384);
  float* cnormG   = ws + 32768;             // guarded region base
  float* cnorm    = cnormG + CG;
  _Float16* feat_h = (_Float16*)(cnorm + NB * NPIX + CG);
  float* featTail = (float*)(feat_h + (size_t)NB * NPIX * 64);

  hipLaunchKernelGGL(k0_prep,   dim3(195), dim3(256), 0, stream, wr, wp, wrAh, wrAl, wpH, cnormG, featTail);
  hipLaunchKernelGGL(k1_reduce, dim3(512), dim3(512), 0, stream, x, wrAh, wrAl, feat_h, cnorm);
  hipLaunchKernelGGL(k23_fused, dim3(512), dim3(512), 0, stream, feat_h, cnorm, wpH, out);
}